// Round 17
// baseline (1338.018 us; speedup 1.0000x reference)
//
#include <hip/hip_runtime.h>
#include <stdint.h>

#define BB 4096
#define JJ 17
#define CC 512

typedef unsigned short u16;
typedef __bf16 bf16x8 __attribute__((ext_vector_type(8)));
typedef float  f32x4  __attribute__((ext_vector_type(4)));

__device__ __forceinline__ float bf2f(u16 u){ return __uint_as_float(((uint32_t)u)<<16); }
__device__ __forceinline__ u16 f2bf(float f){
  uint32_t u = __float_as_uint(f);
  u += 0x7fffu + ((u>>16)&1u);           // round-to-nearest-even
  return (u16)(u>>16);
}
__device__ __forceinline__ void unpk2(uint32_t u, float& lo, float& hi){
  lo = __uint_as_float(u<<16);
  hi = __uint_as_float(u & 0xffff0000u);
}
// tanh-approx GELU: max |err| vs exact-erf ~3e-3 (threshold is 0.166)
__device__ __forceinline__ float gelu_f(float x){
  float x2 = x*x;
  float y2 = x*fmaf(0.0713548162726f, x2, 1.59576912161f);
  float ey = __builtin_amdgcn_exp2f(y2*1.44269504089f);
  return fmaf(-x, __builtin_amdgcn_rcpf(ey+1.f), x);
}
__device__ __forceinline__ void gll16(const void* g, void* l){
  __builtin_amdgcn_global_load_lds(
      (const __attribute__((address_space(1))) void*)g,
      (__attribute__((address_space(3))) void*)l, 16, 0, 0);
}

// ---------------- merged weight f32 -> bf16 convert (7 ranges, 1 launch) ----------------
__global__ void k_cvt7(const float* __restrict__ s0,const float* __restrict__ s1,
                       const float* __restrict__ s2,const float* __restrict__ s3,
                       const float* __restrict__ s4,const float* __restrict__ s5,
                       const float* __restrict__ s6, u16* __restrict__ out){
  int i = blockIdx.x*blockDim.x + threadIdx.x;
  if (i >= 3932160) return;
  const float* src; int off;
  if      (i < 786432)  { src=s0; off=0; }
  else if (i < 1572864) { src=s1; off=786432; }
  else if (i < 1835008) { src=s2; off=1572864; }
  else if (i < 2097152) { src=s3; off=1835008; }
  else if (i < 2621440) { src=s4; off=2097152; }
  else if (i < 3145728) { src=s5; off=2621440; }
  else                  { src=s6; off=3145728; }
  out[i] = f2bf(src[i-off]);
}

// ---------------- token-MLP weight prep: padded bf16 [64][40] and [32][72] ----------------
__global__ void k_tokprep(const float* __restrict__ w1, const float* __restrict__ w2,
                          u16* __restrict__ w1m, u16* __restrict__ w2m){
  int i = blockIdx.x*blockDim.x + threadIdx.x;
  if (i < 2560){ int t=i/40, j=i%40; w1m[i] = (j<17) ? f2bf(w1[t*17+j]) : (u16)0; }
  int k = i - 2560;
  if (k >= 0 && k < 2304){ int j=k/72, t=k%72; w2m[k] = (j<17 && t<64) ? f2bf(w2[j*64+t]) : (u16)0; }
}

// ---------------- pre: LN(over J) + dwconv + GN1 + gelu ----------------
__global__ __launch_bounds__(512) void k_pre(
    const float* __restrict__ x, int b0,
    const float* __restrict__ n1w, const float* __restrict__ n1b,
    const float* __restrict__ dww, const float* __restrict__ dwb,
    const float* __restrict__ gn1w, const float* __restrict__ gn1b,
    u16* __restrict__ xc, u16* __restrict__ hgn)
{
  int b = blockIdx.x, c = threadIdx.x;
  const float* xp = x + (size_t)(b0+b)*JJ*CC + c;
  float v[JJ]; float s = 0.f;
  #pragma unroll
  for (int j=0;j<JJ;j++){ v[j] = xp[(size_t)j*CC]; s += v[j]; }
  float mn = s*(1.f/JJ); float var = 0.f;
  #pragma unroll
  for (int j=0;j<JJ;j++){ float d=v[j]-mn; var += d*d; }
  float rr = rsqrtf(var*(1.f/JJ)+1e-5f);
  float xcv[JJ];
  #pragma unroll
  for (int j=0;j<JJ;j++) xcv[j] = (v[j]-mn)*rr*n1w[j] + n1b[j];
  u16* xo = xc + (size_t)b*JJ*CC + c;
  #pragma unroll
  for (int j=0;j<JJ;j++) xo[(size_t)j*CC] = f2bf(xcv[j]);
  float w0=dww[c*3+0], w1=dww[c*3+1], w2=dww[c*3+2], db=dwb[c];
  float h[JJ];
  #pragma unroll
  for (int j=0;j<JJ;j++){
    float a = db + w1*xcv[j];
    if (j>0)    a += w0*xcv[j-1];
    if (j<JJ-1) a += w2*xcv[j+1];
    h[j] = a;
  }
  float ss=0.f, sq=0.f;
  #pragma unroll
  for (int j=0;j<JJ;j++){ ss += h[j]; sq += h[j]*h[j]; }
  for (int off=32; off; off>>=1){ ss += __shfl_xor(ss,off); sq += __shfl_xor(sq,off); }
  float gm = ss*(1.f/(64.f*JJ));
  float gr = rsqrtf(sq*(1.f/(64.f*JJ)) - gm*gm + 1e-5f);
  float gw = gn1w[c], gb = gn1b[c];
  u16* ho = hgn + (size_t)b*JJ*CC + c;
  #pragma unroll
  for (int j=0;j<JJ;j++){
    float t = (h[j]-gm)*gr*gw + gb;
    ho[(size_t)j*CC] = f2bf(gelu_f(t));
  }
}

// ---------------- 256x256x64 fine 8-phase dbuf-2 MFMA GEMM (m201-style) ----------------
// out[M,N] = A[M,K] @ W[N,K]^T (+bias)(+adds)(+gelu). M%256==0, N%256==0, K%128==0.
// LDS: 2 slots x (A[256][64]+B[256][64]) = 128KB. 8 waves (2Mx4N), per-wave 128x64.
// Per K-tile 4 phases: {ds-subtile | 1 half-tile stage | bar | lgkm0 | 16 MFMA | bar}.
// Ledger: S(t+1,A1/B0/B1)@ph1-3, S(t+2,A0)@ph4; vmcnt(2)@ph4 drains all S(t+1)
// (8 outstanding -> 2), leaving only S(t+2,A0). Tail uses vmcnt(0). Race-free:
// slot-s writes (S(t+2,A0)) occur after slot-s's last ds_read (ph3) + barrier.
template<int DO_GELU, int DO_ADD>
__global__ __launch_bounds__(512,2) void gemm_8p(
    const u16* __restrict__ A, const u16* __restrict__ W, const float* __restrict__ bias,
    u16* __restrict__ out, const u16* __restrict__ add0, const u16* __restrict__ add1,
    int M, int N, int K, int NXT)
{
  __shared__ __align__(16) u16 lds[65536];
  const int tid = threadIdx.x;
  const int wid = tid>>6, lane = tid&63;

  // T1: bijective chunked XCD swizzle
  const int nwg = gridDim.x;
  const int q8 = nwg>>3, r8 = nwg&7;
  const int xcd = blockIdx.x & 7, sub = blockIdx.x >> 3;
  const int wg = (xcd<r8 ? xcd*(q8+1) : r8*(q8+1)+(xcd-r8)*q8) + sub;
  const int n0 = (wg % NXT)*256;
  const int m0 = (wg / NXT)*256;

  const int wm = wid>>2, wn = wid&3;      // 2M x 4N waves, 128x64 out/wave
  const int lr = lane&15, lg = lane>>4;
  const int T  = K>>6;

  // staging: thread covers rows l*64+srow, group tid&7 (16B), source pre-swizzled
  const int srow = tid>>3;
  const int gs = ((tid&7) ^ (srow&7))<<3;     // u16 offset in 64-u16 row
  const u16* pA = A + (size_t)(m0 + srow)*K + gs;
  const u16* pB = W + (size_t)(n0 + srow)*K + gs;
  const size_t r64K  = (size_t)64*K;
  const size_t r128K = (size_t)128*K;
  const int dst = tid*8;

  // ds_read: global group kk*4+lg at row r -> LDS group (kk*4+lg)^(r&7); r&7==lr&7
  const int gk0 = ((0+lg) ^ (lr&7))<<3;
  const int gk1 = ((4+lg) ^ (lr&7))<<3;
  const int aro = wm*128 + lr;            // + mi*16
  const int bro = wn*64  + lr;            // + ni*16

  f32x4 acc[8][4];
  #pragma unroll
  for (int i=0;i<8;i++)
    #pragma unroll
    for (int j=0;j<4;j++) acc[i][j] = (f32x4){0.f,0.f,0.f,0.f};

  bf16x8 aA[2][4], bB0[2][2], bB1[2][2];

  auto ST = [&](const u16* p, int t, int du16){   // one half-tile = 2 gll16
    gll16(p + t*64,        lds + du16 + dst);
    gll16(p + r64K + t*64, lds + du16 + 4096 + dst);
  };

  // prologue: tile0 all 4 halves -> slot0; tile1 A-h0 -> slot1; drain tile0
  ST(pA,        0, 0);
  ST(pA+r128K,  0, 8192);
  ST(pB,        0, 16384);
  ST(pB+r128K,  0, 24576);
  if (T > 1) ST(pA, 1, 32768);
  asm volatile("s_waitcnt vmcnt(2)" ::: "memory");
  __builtin_amdgcn_s_barrier();

  for (int t=0; t<T; ++t){
    const int s = (t&1)<<15, o = s^32768;
    const bool m1 = (t+1 < T), m2 = (t+2 < T);
    // ---- phase 1: A mi0-3 + B ni0-1 ; stage S(t+1,A1) ; MFMA Q(0,0) ----
    #pragma unroll
    for (int i=0;i<4;i++){
      const int rb = s + (aro + i*16)*64;
      aA[0][i] = *(const bf16x8*)&lds[rb + gk0];
      aA[1][i] = *(const bf16x8*)&lds[rb + gk1];
    }
    #pragma unroll
    for (int j=0;j<2;j++){
      const int rb = s + 16384 + (bro + j*16)*64;
      bB0[0][j] = *(const bf16x8*)&lds[rb + gk0];
      bB0[1][j] = *(const bf16x8*)&lds[rb + gk1];
    }
    if (m1) ST(pA+r128K, t+1, o+8192);
    __builtin_amdgcn_s_barrier();
    asm volatile("s_waitcnt lgkmcnt(0)" ::: "memory");
    __builtin_amdgcn_s_setprio(1);
    #pragma unroll
    for (int kk=0;kk<2;kk++)
      #pragma unroll
      for (int i=0;i<4;i++)
        #pragma unroll
        for (int j=0;j<2;j++)
          acc[i][j] = __builtin_amdgcn_mfma_f32_16x16x32_bf16(aA[kk][i], bB0[kk][j], acc[i][j], 0,0,0);
    __builtin_amdgcn_s_setprio(0);
    __builtin_amdgcn_s_barrier();
    // ---- phase 2: B ni2-3 ; stage S(t+1,B0) ; MFMA Q(0,1) ----
    #pragma unroll
    for (int j=0;j<2;j++){
      const int rb = s + 16384 + (bro + (2+j)*16)*64;
      bB1[0][j] = *(const bf16x8*)&lds[rb + gk0];
      bB1[1][j] = *(const bf16x8*)&lds[rb + gk1];
    }
    if (m1) ST(pB, t+1, o+16384);
    __builtin_amdgcn_s_barrier();
    asm volatile("s_waitcnt lgkmcnt(0)" ::: "memory");
    __builtin_amdgcn_s_setprio(1);
    #pragma unroll
    for (int kk=0;kk<2;kk++)
      #pragma unroll
      for (int i=0;i<4;i++)
        #pragma unroll
        for (int j=0;j<2;j++)
          acc[i][2+j] = __builtin_amdgcn_mfma_f32_16x16x32_bf16(aA[kk][i], bB1[kk][j], acc[i][2+j], 0,0,0);
    __builtin_amdgcn_s_setprio(0);
    __builtin_amdgcn_s_barrier();
    // ---- phase 3: A mi4-7 ; stage S(t+1,B1) ; MFMA Q(1,0) ----
    #pragma unroll
    for (int i=0;i<4;i++){
      const int rb = s + (aro + (4+i)*16)*64;
      aA[0][i] = *(const bf16x8*)&lds[rb + gk0];
      aA[1][i] = *(const bf16x8*)&lds[rb + gk1];
    }
    if (m1) ST(pB+r128K, t+1, o+24576);
    __builtin_amdgcn_s_barrier();
    asm volatile("s_waitcnt lgkmcnt(0)" ::: "memory");
    __builtin_amdgcn_s_setprio(1);
    #pragma unroll
    for (int kk=0;kk<2;kk++)
      #pragma unroll
      for (int i=0;i<4;i++)
        #pragma unroll
        for (int j=0;j<2;j++)
          acc[4+i][j] = __builtin_amdgcn_mfma_f32_16x16x32_bf16(aA[kk][i], bB0[kk][j], acc[4+i][j], 0,0,0);
    __builtin_amdgcn_s_setprio(0);
    __builtin_amdgcn_s_barrier();
    // ---- phase 4: stage S(t+2,A0) ; counted vmcnt ; MFMA Q(1,1) ----
    if (m2) ST(pA, t+2, s);
    if (m2) asm volatile("s_waitcnt vmcnt(2)" ::: "memory");
    else    asm volatile("s_waitcnt vmcnt(0)" ::: "memory");
    __builtin_amdgcn_s_barrier();
    __builtin_amdgcn_s_setprio(1);
    #pragma unroll
    for (int kk=0;kk<2;kk++)
      #pragma unroll
      for (int i=0;i<4;i++)
        #pragma unroll
        for (int j=0;j<2;j++)
          acc[4+i][2+j] = __builtin_amdgcn_mfma_f32_16x16x32_bf16(aA[kk][i], bB1[kk][j], acc[4+i][2+j], 0,0,0);
    __builtin_amdgcn_s_setprio(0);
    __builtin_amdgcn_s_barrier();
  }

  const int rbase = lg*4;
  #pragma unroll
  for (int i=0;i<8;i++){
    #pragma unroll
    for (int j=0;j<4;j++){
      const int col  = n0 + wn*64 + j*16 + lr;
      const int row0 = m0 + wm*128 + i*16 + rbase;
      const float bvl = bias[col];
      #pragma unroll
      for (int r=0;r<4;r++){
        size_t idx = (size_t)(row0+r)*N + col;
        float v = acc[i][j][r] + bvl;
        if (DO_ADD)  v += bf2f(add0[idx]) + bf2f(add1[idx]);
        if (DO_GELU) v = gelu_f(v);
        out[idx] = f2bf(v);
      }
    }
  }
}

// ---------------- adj contraction; FINAL: out_f32 = contraction + tsum(bf16) ----------------
template<int FINAL>
__global__ __launch_bounds__(512) void k_gcn2(
    const u16* __restrict__ G, const float* __restrict__ adj,
    u16* __restrict__ xg,
    const u16* __restrict__ tsum, int b0,
    float* __restrict__ out)
{
  __shared__ __align__(16) float adjp[51*20];
  const int tid = threadIdx.x;
  for (int i=tid; i<1020; i+=512){
    int r=i/20, cl=i%20;
    adjp[i] = (cl<17) ? adj[r*17+cl] : 0.f;
  }
  __syncthreads();

  const int sl  = tid>>7;
  const int l   = tid&127;
  const int c0  = l*4;
  const int bl  = blockIdx.x*4 + sl;

  float acc[JJ][4];
  #pragma unroll
  for (int w=0;w<JJ;w++)
    #pragma unroll
    for (int e=0;e<4;e++) acc[w][e]=0.f;

  const u16* gbase = G + (size_t)bl*JJ*1536 + c0;
  #pragma unroll 3
  for (int kv=0; kv<51; kv++){
    const int k = kv/JJ, v = kv - k*JJ;
    uint2 yu = *(const uint2*)(gbase + (size_t)v*1536 + k*512);
    float y0,y1,y2,y3;
    unpk2(yu.x, y0, y1);
    unpk2(yu.y, y2, y3);
    const f32x4* arow = (const f32x4*)&adjp[kv*20];
    f32x4 a0=arow[0], a1=arow[1], a2=arow[2], a3=arow[3];
    float a16 = adjp[kv*20+16];
    float ar[JJ] = {a0[0],a0[1],a0[2],a0[3], a1[0],a1[1],a1[2],a1[3],
                    a2[0],a2[1],a2[2],a2[3], a3[0],a3[1],a3[2],a3[3], a16};
    #pragma unroll
    for (int w=0;w<JJ;w++){
      acc[w][0] += y0*ar[w];
      acc[w][1] += y1*ar[w];
      acc[w][2] += y2*ar[w];
      acc[w][3] += y3*ar[w];
    }
  }

  if (FINAL==0){
    u16* xo = xg + (size_t)bl*JJ*CC + c0;
    #pragma unroll
    for (int w=0;w<JJ;w++){
      uint2 o;
      o.x = (uint32_t)f2bf(acc[w][0]) | ((uint32_t)f2bf(acc[w][1])<<16);
      o.y = (uint32_t)f2bf(acc[w][2]) | ((uint32_t)f2bf(acc[w][3])<<16);
      *(uint2*)(xo + (size_t)w*CC) = o;
    }
  } else {
    const size_t lb = (size_t)bl*JJ*CC + c0;
    const size_t gb = (size_t)(b0+bl)*JJ*CC + c0;
    #pragma unroll
    for (int w=0;w<JJ;w++){
      uint2 tu = *(const uint2*)(tsum + lb + (size_t)w*CC);
      float t0,t1,t2,t3;
      unpk2(tu.x, t0, t1);
      unpk2(tu.y, t2, t3);
      f32x4 o;
      o[0]=acc[w][0]+t0; o[1]=acc[w][1]+t1;
      o[2]=acc[w][2]+t2; o[3]=acc[w][3]+t3;
      *(f32x4*)(out + gb + (size_t)w*CC) = o;
    }
  }
}

// ---------------- attention over joints: one wave per head, vectorized ----------------
__global__ __launch_bounds__(512) void k_attn(const u16* __restrict__ Gqkv, u16* __restrict__ sga){
  __shared__ __align__(16) u16 qs[8*17*72];
  __shared__ __align__(16) u16 ks_[8*17*72];
  __shared__ __align__(16) float at[8*17*20];
  int b = blockIdx.x, tid = threadIdx.x;
  int h = tid>>6, d = tid&63;
  const u16* base = Gqkv + (size_t)b*JJ*1536;
  float vv[JJ];
  #pragma unroll
  for (int i=0;i<JJ;i++){
    qs [(h*JJ+i)*72 + d] = base[(size_t)i*1536 +        h*64 + d];
    ks_[(h*JJ+i)*72 + d] = base[(size_t)i*1536 +  512 + h*64 + d];
    vv[i] = bf2f(base[(size_t)i*1536 + 1024 + h*64 + d]);
  }
  __syncthreads();
  for (int p=d; p<289; p+=64){
    int i=p/JJ, j=p-i*JJ;
    const u16* qrow = &qs [(h*JJ+i)*72];
    const u16* krow = &ks_[(h*JJ+j)*72];
    float a=0.f;
    #pragma unroll
    for (int t=0;t<8;t++){
      bf16x8 q8 = *(const bf16x8*)&qrow[t*8];
      bf16x8 k8 = *(const bf16x8*)&krow[t*8];
      #pragma unroll
      for (int e=0;e<8;e++) a += (float)q8[e]*(float)k8[e];
    }
    at[(h*JJ+i)*20 + j] = a*0.125f;
  }
  __syncthreads();
  if (d < JJ){
    float* row = &at[(h*JJ+d)*20];
    f32x4 r0=((f32x4*)row)[0], r1=((f32x4*)row)[1], r2=((f32x4*)row)[2], r3=((f32x4*)row)[3];
    float e16=row[16];
    float rv[JJ]={r0[0],r0[1],r0[2],r0[3],r1[0],r1[1],r1[2],r1[3],
                  r2[0],r2[1],r2[2],r2[3],r3[0],r3[1],r3[2],r3[3],e16};
    float mx=-1e30f;
    #pragma unroll
    for (int j=0;j<JJ;j++) mx=fmaxf(mx,rv[j]);
    float sm=0.f;
    #pragma unroll
    for (int j=0;j<JJ;j++){ rv[j]=__builtin_amdgcn_exp2f((rv[j]-mx)*1.44269504089f); sm+=rv[j]; }
    float inv=1.f/sm;
    #pragma unroll
    for (int j=0;j<JJ;j++) row[j]=rv[j]*inv;
  }
  __syncthreads();
  #pragma unroll
  for (int i=0;i<JJ;i++){
    const float* row = &at[(h*JJ+i)*20];
    f32x4 r0=((const f32x4*)row)[0], r1=((const f32x4*)row)[1],
          r2=((const f32x4*)row)[2], r3=((const f32x4*)row)[3];
    float a = r0[0]*vv[0]+r0[1]*vv[1]+r0[2]*vv[2]+r0[3]*vv[3]
            + r1[0]*vv[4]+r1[1]*vv[5]+r1[2]*vv[6]+r1[3]*vv[7]
            + r2[0]*vv[8]+r2[1]*vv[9]+r2[2]*vv[10]+r2[3]*vv[11]
            + r3[0]*vv[12]+r3[1]*vv[13]+r3[2]*vv[14]+r3[3]*vv[15]
            + row[16]*vv[16];
    sga[((size_t)b*JJ+i)*CC + h*64 + d] = f2bf(a);
  }
}

// ---------------- token MLP v4: MFMA (one sample/block, 4 waves, 2 c-passes) ----------------
__global__ __launch_bounds__(256) void k_tok(const u16* __restrict__ Hpw,
    const u16* __restrict__ w1m, const u16* __restrict__ w2m,
    const float* __restrict__ b1, const float* __restrict__ b2,
    u16* __restrict__ h2o){
  __shared__ __align__(16) u16 lds[31488];
  __shared__ float b1s[64], b2s[32];
  const int tid = threadIdx.x, wid = tid>>6, lane = tid&63;
  const int lr = lane&15, lg = lane>>4;
  const int bl = blockIdx.x;
  const f32x4 zz = {0.f,0.f,0.f,0.f};

  for (int i=tid; i<2560; i+=256) lds[26624+i] = w1m[i];
  for (int i=tid; i<2304; i+=256) lds[29184+i] = w2m[i];
  if (tid<64) b1s[tid] = b1[tid];
  if (tid<32) b2s[tid] = (tid<17) ? b2[tid] : 0.f;
  {
    const int base = tid*40;
    lds[base+17]=0; lds[base+18]=0; lds[base+19]=0;
    #pragma unroll
    for (int q=0;q<5;q++) *(uint2*)&lds[base+20+q*4] = (uint2){0u,0u};
  }
  __syncthreads();

  const u16* hp = Hpw + (size_t)bl*JJ*CC;
  u16* op = h2o + (size_t)bl*JJ*CC;

  for (int pass=0; pass<2; ++pass){
    const int cbase = pass*256;
    for (int idx=tid; idx<1088; idx+=256){
      int j = idx>>6, cq = (idx&63)<<2;
      uint2 u = *(const uint2*)(hp + (size_t)j*CC + cbase + cq);
      lds[(cq  )*40 + j] = (u16)(u.x & 0xffffu);
      lds[(cq+1)*40 + j] = (u16)(u.x >> 16);
      lds[(cq+2)*40 + j] = (u16)(u.y & 0xffffu);
      lds[(cq+3)*40 + j] = (u16)(u.y >> 16);
    }
    __syncthreads();

    // ---- fc1 ----
    bf16x8 av1[4];
    #pragma unroll
    for (int mt=0;mt<4;mt++) av1[mt] = *(const bf16x8*)&lds[26624 + (mt*16+lr)*40 + lg*8];
    #pragma unroll
    for (int nt=0;nt<4;nt++){
      const int cl = wid*64 + nt*16 + lr;
      bf16x8 bv = *(const bf16x8*)&lds[cl*40 + lg*8];
      #pragma unroll
      for (int mt=0;mt<4;mt++){
        f32x4 ac = __builtin_amdgcn_mfma_f32_16x16x32_bf16(av1[mt], bv, zz, 0,0,0);
        const int t0 = mt*16 + lg*4;
        float g0 = gelu_f(ac[0] + b1s[t0+0]);
        float g1 = gelu_f(ac[1] + b1s[t0+1]);
        float g2 = gelu_f(ac[2] + b1s[t0+2]);
        float g3 = gelu_f(ac[3] + b1s[t0+3]);
        uint2 pk;
        pk.x = (uint32_t)f2bf(g0) | ((uint32_t)f2bf(g1)<<16);
        pk.y = (uint32_t)f2bf(g2) | ((uint32_t)f2bf(g3)<<16);
        const int gi = (10240 + cl*64 + t0) ^ ((cl&7)<<3);
        *(uint2*)&lds[gi] = pk;
      }
    }
    asm volatile("s_waitcnt lgkmcnt(0)" ::: "memory");
    __builtin_amdgcn_sched_barrier(0);

    // ---- fc2 ----
    bf16x8 av2[2][2];
    #pragma unroll
    for (int mt=0;mt<2;mt++)
      #pragma unroll
      for (int kt=0;kt<2;kt++)
        av2[mt][kt] = *(const bf16x8*)&lds[29184 + (mt*16+lr)*72 + kt*32 + lg*8];
    #pragma unroll
    for (int nt=0;nt<4;nt++){
      const int cl = wid*64 + nt*16 + lr;
      f32x4 a20 = zz, a21 = zz;
      #pragma unroll
      for (int kt=0;kt<2;kt++){
        const int gi = (10240 + cl*64 + kt*32 + lg*8) ^ ((cl&7)<<3);
        bf16x8 bv2 = *(const bf16x8*)&lds[gi];
        a20 = __builtin_amdgcn_mfma_f32_16x16x32_bf16(av2[0][kt], bv2, a20, 0,0,0);
        a21 = __builtin_amdgcn_mfma_f32_16x16x32_bf16(av2[1][kt], bv2, a21, 0,0,0);
      }
      const int c = cbase + cl;
      #pragma unroll
      for (int r=0;r<4;r++){
        const int j = lg*4 + r;
        op[(size_t)j*CC + c] = f2bf(a20[r] + b2s[j]);
      }
      if (lg==0) op[(size_t)16*CC + c] = f2bf(a21[0] + b2s[16]);
    }
    __syncthreads();
  }
}

// ---------------- fuse part A: GN(gnf)+gelu ; tsum = gelu + x (bf16), 4ch/thread ----------
__global__ __launch_bounds__(512) void k_fuse_a(const u16* __restrict__ s,
    const float* __restrict__ x, int b0,
    const float* __restrict__ gfw, const float* __restrict__ gfb,
    u16* __restrict__ tsum){
  const int tid = threadIdx.x;
  const int sl  = tid>>7;
  const int l   = tid&127;
  const int c0  = l*4;
  const int bl  = blockIdx.x*4 + sl;

  const u16* sp = s + (size_t)bl*JJ*CC + c0;
  float sv[JJ][4];
  float ss=0.f, sq=0.f;
  #pragma unroll
  for (int j=0;j<JJ;j++){
    uint2 u = *(const uint2*)(sp + (size_t)j*CC);
    unpk2(u.x, sv[j][0], sv[j][1]);
    unpk2(u.y, sv[j][2], sv[j][3]);
    #pragma unroll
    for (int e=0;e<4;e++){ ss += sv[j][e]; sq = fmaf(sv[j][e], sv[j][e], sq); }
  }
  #pragma unroll
  for (int off=8; off; off>>=1){ ss += __shfl_xor(ss,off); sq += __shfl_xor(sq,off); }
  float gm = ss*(1.f/1088.f);
  float gr = rsqrtf(sq*(1.f/1088.f) - gm*gm + 1e-5f);

  f32x4 gw = *(const f32x4*)(gfw + c0);
  f32x4 gb = *(const f32x4*)(gfb + c0);
  const float* xp = x + (size_t)(b0+bl)*JJ*CC + c0;
  u16* tp = tsum + (size_t)bl*JJ*CC + c0;
  #pragma unroll
  for (int j=0;j<JJ;j++){
    f32x4 xv = *(const f32x4*)(xp + (size_t)j*CC);
    float t0 = gelu_f((sv[j][0]-gm)*gr*gw[0] + gb[0]) + xv[0];
    float t1 = gelu_f((sv[j][1]-gm)*gr*gw[1] + gb[1]) + xv[1];
    float t2 = gelu_f((sv[j][2]-gm)*gr*gw[2] + gb[2]) + xv[2];
    float t3 = gelu_f((sv[j][3]-gm)*gr*gw[3] + gb[3]) + xv[3];
    uint2 o;
    o.x = (uint32_t)f2bf(t0) | ((uint32_t)f2bf(t1)<<16);
    o.y = (uint32_t)f2bf(t2) | ((uint32_t)f2bf(t3)<<16);
    *(uint2*)(tp + (size_t)j*CC) = o;
  }
}

// ---------------- fuse part B: LN over C, one wave per token ----------------
__global__ __launch_bounds__(512) void k_ln(const u16* __restrict__ tsum,
    const float* __restrict__ n2w, const float* __restrict__ n2b,
    u16* __restrict__ xn){
  const int wid = threadIdx.x>>6, lane = threadIdx.x&63;
  const size_t tk = (size_t)blockIdx.x*8 + wid;
  const u16* tp = tsum + tk*CC + lane*8;
  uint4 u = *(const uint4*)tp;
  float v[8];
  unpk2(u.x, v[0], v[1]);
  unpk2(u.y, v[2], v[3]);
  unpk2(u.z, v[4], v[5]);
  unpk2(u.w, v[6], v[7]);
  float ss=0.f, sq=0.f;
  #pragma unroll
  for (int e=0;e<8;e++){ ss += v[e]; sq = fmaf(v[e], v[e], sq); }
  #pragma unroll
  for (int off=32; off; off>>=1){ ss += __shfl_xor(ss,off); sq += __shfl_xor(sq,off); }
  float mn = ss*(1.f/512.f);
  float r2 = rsqrtf(sq*(1.f/512.f) - mn*mn + 1e-5f);
  f32x4 w0 = *(const f32x4*)(n2w + lane*8);
  f32x4 w1 = *(const f32x4*)(n2w + lane*8 + 4);
  f32x4 b0 = *(const f32x4*)(n2b + lane*8);
  f32x4 b1 = *(const f32x4*)(n2b + lane*8 + 4);
  float wv[8] = {w0[0],w0[1],w0[2],w0[3], w1[0],w1[1],w1[2],w1[3]};
  float bv[8] = {b0[0],b0[1],b0[2],b0[3], b1[0],b1[1],b1[2],b1[3]};
  u16 o[8];
  #pragma unroll
  for (int e=0;e<8;e++) o[e] = f2bf((v[e]-mn)*r2*wv[e] + bv[e]);
  uint4 pk;
  pk.x = (uint32_t)o[0] | ((uint32_t)o[1]<<16);
  pk.y = (uint32_t)o[2] | ((uint32_t)o[3]<<16);
  pk.z = (uint32_t)o[4] | ((uint32_t)o[5]<<16);
  pk.w = (uint32_t)o[6] | ((uint32_t)o[7]<<16);
  *(uint4*)(xn + tk*CC + lane*8) = pk;
}

extern "C" void kernel_launch(void* const* d_in, const int* in_sizes, int n_in,
                              void* d_out, int out_size, void* d_ws, size_t ws_size,
                              hipStream_t stream)
{
  const float* x      = (const float*)d_in[0];
  const float* adj    = (const float*)d_in[1];
  const float* n1w    = (const float*)d_in[2];
  const float* n1b    = (const float*)d_in[3];
  const float* gcn1_w = (const float*)d_in[4];
  const float* gcn1_b = (const float*)d_in[5];
  const float* dw_w   = (const float*)d_in[6];
  const float* dw_b   = (const float*)d_in[7];
  const float* gn1_w  = (const float*)d_in[8];
  const float* gn1_b  = (const float*)d_in[9];
  const float* pw_w   = (const float*)d_in[10];
  const float* pw_b   = (const float*)d_in[11];
  const float* m1w1   = (const float*)d_in[12];
  const float* m1b1   = (const float*)d_in[13];
  const float* m1w2   = (const float*)d_in[14];
  const float* m1b2   = (const float*)d_in[15];
  const float* qkv_w  = (const float*)d_in[16];
  const float* qkv_b  = (const float*)d_in[17];
  const float* proj_w = (const float*)d_in[18];
  const float* proj_b = (const float*)d_in[19];
  const float* gnf_w  = (const float*)d_in[20];
  const float* gnf_b  = (const float*)d_in[21];
  const float* n2w    = (const float*)d_in[22];
  const float* n2b    = (const float*)d_in[23];
  const float* m2w1   = (const float*)d_in[24];
  const float* m2b1   = (const float*)d_in[25];
  const float* m2w2   = (const float*)d_in[26];
  const float* m2b2   = (const float*)d_in[27];
  const float* gcn2_w = (const float*)d_in[28];
  const float* gcn2_b = (const float*)d_in[29];
  float* out = (float*)d_out;

  char* ws = (char*)d_ws;
  const size_t WBYTES = (size_t)3932160*2;
  const size_t TPBYTES = (2560+2304)*2;

  const int cands[5] = {4096,2048,1024,512,256};
  int NB = 0;
  for (int ci=0; ci<5; ci++){
    size_t need = WBYTES + TPBYTES + (size_t)cands[ci]*JJ*2*(1536 + 4*512);
    if (need <= ws_size){ NB = cands[ci]; break; }
  }
  if (NB == 0) return;

  u16* wb = (u16*)ws;
  u16* w1m = (u16*)(ws + WBYTES);
  u16* w2m = w1m + 2560;
  char* p = ws + WBYTES + TPBYTES;
  const size_t SZ_BIGc = (size_t)NB*JJ*1536*2;
  const size_t SZTc    = (size_t)NB*JJ*512*2;
  u16* big = (u16*)p;               p += SZ_BIGc;
  u16* t0  = (u16*)p;               p += SZTc;   // xc -> Hpw -> s -> m2
  u16* t1  = (u16*)p;               p += SZTc;   // hgn -> h2
  u16* t2  = (u16*)p;               p += SZTc;   // xg -> xn
  u16* t3  = (u16*)p;                            // sga -> tsum

  u16 *wg1=wb, *wqkv=wb+786432, *wpw=wb+1572864, *wproj=wb+1835008,
      *wm1=wb+2097152, *wm2=wb+2621440, *wg2=wb+3145728;

  k_cvt7<<<(3932160+255)/256,256,0,stream>>>(gcn1_w,qkv_w,pw_w,proj_w,m2w1,m2w2,gcn2_w,wb);
  k_tokprep<<<19,256,0,stream>>>(m1w1,m1w2,w1m,w2m);

  const int M2 = NB*JJ;
  const int MT = M2/256;
  for (int b0 = 0; b0 < BB; b0 += NB){
    k_pre<<<NB,512,0,stream>>>(x,b0,n1w,n1b,dw_w,dw_b,gn1_w,gn1_b, t0/*xc*/, t1/*hgn*/);
    // GCN1 (N=1536 -> NXT=6)
    gemm_8p<0,0><<<MT*6,512,0,stream>>>(t0,wg1,gcn1_b,big,nullptr,nullptr,M2,1536,512,6);
    k_gcn2<0><<<NB/4,512,0,stream>>>(big,adj,t2/*xg*/,nullptr,0,nullptr);
    // QKV + attention
    gemm_8p<0,0><<<MT*6,512,0,stream>>>(t0,wqkv,qkv_b,big,nullptr,nullptr,M2,1536,512,6);
    k_attn<<<NB,512,0,stream>>>(big,t3/*sga*/);
    // pw + token MLP  (xc dead -> t0 reused for Hpw)
    gemm_8p<0,0><<<MT*2,512,0,stream>>>(t1,wpw,pw_b,t0/*Hpw*/,nullptr,nullptr,M2,512,512,2);
    k_tok<<<NB,256,0,stream>>>(t0,w1m,w2m,m1b1,m1b2,t1/*h2*/);
    // proj + branch merge: s = proj(sga)+b + xg + h2   (sga consumed -> t3 free)
    gemm_8p<0,1><<<MT*2,512,0,stream>>>(t3,wproj,proj_b,t0/*s*/,t2,t1,M2,512,512,2);
    // GN(gnf)+gelu ; tsum=rc+x -> t3 ; LN2(tsum) -> xn (t2)
    k_fuse_a<<<NB/4,512,0,stream>>>(t0,x,b0,gnf_w,gnf_b,t3/*tsum*/);
    k_ln<<<M2/8,512,0,stream>>>(t3,n2w,n2b,t2/*xn*/);
    // MLP2
    gemm_8p<1,0><<<MT*4,512,0,stream>>>(t2,wm1,m2b1,big/*m*/,nullptr,nullptr,M2,1024,512,4);
    gemm_8p<0,0><<<MT*2,512,0,stream>>>(big,wm2,m2b2,t0/*m2*/,nullptr,nullptr,M2,512,1024,2);
    // GCN2
    gemm_8p<0,0><<<MT*6,512,0,stream>>>(t0,wg2,gcn2_b,big/*G2*/,nullptr,nullptr,M2,1536,512,6);
    k_gcn2<1><<<NB/4,512,0,stream>>>(big,adj,nullptr,t3/*tsum*/,b0,out);
  }
}

// Round 18
// 1273.094 us; speedup vs baseline: 1.0510x; 1.0510x over previous
//
#include <hip/hip_runtime.h>
#include <stdint.h>

#define BB 4096
#define JJ 17
#define CC 512

typedef unsigned short u16;
typedef __bf16 bf16x8 __attribute__((ext_vector_type(8)));
typedef float  f32x4  __attribute__((ext_vector_type(4)));

__device__ __forceinline__ float bf2f(u16 u){ return __uint_as_float(((uint32_t)u)<<16); }
__device__ __forceinline__ u16 f2bf(float f){
  uint32_t u = __float_as_uint(f);
  u += 0x7fffu + ((u>>16)&1u);           // round-to-nearest-even
  return (u16)(u>>16);
}
__device__ __forceinline__ void unpk2(uint32_t u, float& lo, float& hi){
  lo = __uint_as_float(u<<16);
  hi = __uint_as_float(u & 0xffff0000u);
}
// tanh-approx GELU: max |err| vs exact-erf ~3e-3 (threshold is 0.166)
__device__ __forceinline__ float gelu_f(float x){
  float x2 = x*x;
  float y2 = x*fmaf(0.0713548162726f, x2, 1.59576912161f);
  float ey = __builtin_amdgcn_exp2f(y2*1.44269504089f);
  return fmaf(-x, __builtin_amdgcn_rcpf(ey+1.f), x);
}
__device__ __forceinline__ void gll16(const void* g, void* l){
  __builtin_amdgcn_global_load_lds(
      (const __attribute__((address_space(1))) void*)g,
      (__attribute__((address_space(3))) void*)l, 16, 0, 0);
}

// ---------------- merged weight f32 -> bf16 convert (7 ranges, 1 launch) ----------------
__global__ void k_cvt7(const float* __restrict__ s0,const float* __restrict__ s1,
                       const float* __restrict__ s2,const float* __restrict__ s3,
                       const float* __restrict__ s4,const float* __restrict__ s5,
                       const float* __restrict__ s6, u16* __restrict__ out){
  int i = blockIdx.x*blockDim.x + threadIdx.x;
  if (i >= 3932160) return;
  const float* src; int off;
  if      (i < 786432)  { src=s0; off=0; }
  else if (i < 1572864) { src=s1; off=786432; }
  else if (i < 1835008) { src=s2; off=1572864; }
  else if (i < 2097152) { src=s3; off=1835008; }
  else if (i < 2621440) { src=s4; off=2097152; }
  else if (i < 3145728) { src=s5; off=2621440; }
  else                  { src=s6; off=3145728; }
  out[i] = f2bf(src[i-off]);
}

// ---------------- token-MLP weight prep: padded bf16 [64][40] and [32][72] ----------------
__global__ void k_tokprep(const float* __restrict__ w1, const float* __restrict__ w2,
                          u16* __restrict__ w1m, u16* __restrict__ w2m){
  int i = blockIdx.x*blockDim.x + threadIdx.x;
  if (i < 2560){ int t=i/40, j=i%40; w1m[i] = (j<17) ? f2bf(w1[t*17+j]) : (u16)0; }
  int k = i - 2560;
  if (k >= 0 && k < 2304){ int j=k/72, t=k%72; w2m[k] = (j<17 && t<64) ? f2bf(w2[j*64+t]) : (u16)0; }
}

// ---------------- pre v2: LN(over J) + dwconv + GN1 + gelu ; 4 samples/block, 4 ch/thread ----
__global__ __launch_bounds__(512) void k_pre(
    const float* __restrict__ x, int b0,
    const float* __restrict__ n1w, const float* __restrict__ n1b,
    const float* __restrict__ dww, const float* __restrict__ dwb,
    const float* __restrict__ gn1w, const float* __restrict__ gn1b,
    u16* __restrict__ xc, u16* __restrict__ hgn)
{
  const int tid = threadIdx.x;
  const int sl = tid>>7, l = tid&127, c0 = l*4;
  const int bl = blockIdx.x*4 + sl;
  const float* xp = x + (size_t)(b0+bl)*JJ*CC + c0;

  float v[JJ][4];
  float s0=0.f,s1=0.f,s2=0.f,s3=0.f;
  #pragma unroll
  for (int j=0;j<JJ;j++){
    f32x4 xv = *(const f32x4*)(xp + (size_t)j*CC);
    v[j][0]=xv[0]; v[j][1]=xv[1]; v[j][2]=xv[2]; v[j][3]=xv[3];
    s0+=xv[0]; s1+=xv[1]; s2+=xv[2]; s3+=xv[3];
  }
  float mn[4] = {s0*(1.f/JJ), s1*(1.f/JJ), s2*(1.f/JJ), s3*(1.f/JJ)};
  float var[4] = {0.f,0.f,0.f,0.f};
  #pragma unroll
  for (int j=0;j<JJ;j++)
    #pragma unroll
    for (int e=0;e<4;e++){ float d=v[j][e]-mn[e]; var[e]=fmaf(d,d,var[e]); }
  float rr[4];
  #pragma unroll
  for (int e=0;e<4;e++) rr[e] = rsqrtf(var[e]*(1.f/JJ)+1e-5f);

  u16* xo = xc + (size_t)bl*JJ*CC + c0;
  #pragma unroll
  for (int j=0;j<JJ;j++){
    float wj = n1w[j], bj = n1b[j];
    #pragma unroll
    for (int e=0;e<4;e++) v[j][e] = (v[j][e]-mn[e])*rr[e]*wj + bj;
    uint2 o;
    o.x = (uint32_t)f2bf(v[j][0]) | ((uint32_t)f2bf(v[j][1])<<16);
    o.y = (uint32_t)f2bf(v[j][2]) | ((uint32_t)f2bf(v[j][3])<<16);
    *(uint2*)(xo + (size_t)j*CC) = o;
  }

  // dw weights: 12 consecutive floats -> de-interleave
  f32x4 d0 = *(const f32x4*)(dww + (size_t)c0*3);
  f32x4 d1 = *(const f32x4*)(dww + (size_t)c0*3 + 4);
  f32x4 d2 = *(const f32x4*)(dww + (size_t)c0*3 + 8);
  float w0[4]={d0[0],d0[3],d1[2],d2[1]};
  float w1[4]={d0[1],d1[0],d1[3],d2[2]};
  float w2[4]={d0[2],d1[1],d2[0],d2[3]};
  f32x4 db4 = *(const f32x4*)(dwb + c0);

  // GN stats over group = 64 ch (16 lanes) x 17 j ; h computed on the fly
  float ss=0.f, sq=0.f;
  #pragma unroll
  for (int j=0;j<JJ;j++){
    #pragma unroll
    for (int e=0;e<4;e++){
      float h = fmaf(w1[e], v[j][e], db4[e]);
      if (j>0)    h = fmaf(w0[e], v[j-1][e], h);
      if (j<JJ-1) h = fmaf(w2[e], v[j+1][e], h);
      ss += h; sq = fmaf(h,h,sq);
    }
  }
  #pragma unroll
  for (int off=8; off; off>>=1){ ss += __shfl_xor(ss,off); sq += __shfl_xor(sq,off); }
  float gm = ss*(1.f/1088.f);
  float gr = rsqrtf(sq*(1.f/1088.f) - gm*gm + 1e-5f);

  f32x4 gw4 = *(const f32x4*)(gn1w + c0);
  f32x4 gb4 = *(const f32x4*)(gn1b + c0);
  u16* ho = hgn + (size_t)bl*JJ*CC + c0;
  #pragma unroll
  for (int j=0;j<JJ;j++){
    float t[4];
    #pragma unroll
    for (int e=0;e<4;e++){
      float h = fmaf(w1[e], v[j][e], db4[e]);
      if (j>0)    h = fmaf(w0[e], v[j-1][e], h);
      if (j<JJ-1) h = fmaf(w2[e], v[j+1][e], h);
      t[e] = gelu_f((h-gm)*gr*gw4[e] + gb4[e]);
    }
    uint2 o;
    o.x = (uint32_t)f2bf(t[0]) | ((uint32_t)f2bf(t[1])<<16);
    o.y = (uint32_t)f2bf(t[2]) | ((uint32_t)f2bf(t[3])<<16);
    *(uint2*)(ho + (size_t)j*CC) = o;
  }
}

// ---------------- 128x256x32 ring-3 counted-vmcnt MFMA GEMM, 8 waves (champion) ----------
template<int DO_GELU, int DO_ADD>
__global__ __launch_bounds__(512,4) void gemm_r5(
    const u16* __restrict__ A, const u16* __restrict__ W, const float* __restrict__ bias,
    u16* __restrict__ out, const u16* __restrict__ add0, const u16* __restrict__ add1,
    int M, int N, int K, int NXT)
{
  __shared__ __align__(16) u16 lds[36864];   // 3 x 12288 u16 (24KB slots)
  const int tid = threadIdx.x;
  const int wid = tid>>6, lane = tid&63;

  const int nwg = gridDim.x;
  const int q8 = nwg>>3, r8 = nwg&7;
  const int xcd = blockIdx.x & 7, sub = blockIdx.x >> 3;
  const int wg = (xcd<r8 ? xcd*(q8+1) : r8*(q8+1)+(xcd-r8)*q8) + sub;
  const int n0 = (wg % NXT)*256;
  const int m0 = (wg / NXT)*128;

  const int wm = wid>>2, wn = wid&3;      // 2M x 4N waves, 64x64 out per wave
  const int lr = lane&15, lg = lane>>4;
  const int T  = K>>5;

  const int agsw = ((tid&3) ^ ((tid>>3)&3))<<3;
  const u16* gA  = A + (size_t)(m0 + (tid>>2))*K + agsw;
  const u16* gB0 = W + (size_t)(n0 + (tid>>2))*K + agsw;
  const u16* gB1 = W + (size_t)(n0 + 128 + (tid>>2))*K + agsw;
  const int dstl = tid*8;

  const int g8 = (lg ^ ((lr>>1)&3))<<3;
  const int offA0 = (wm*64+lr)*32 + g8;
  const int offB0 = 4096 + (wn*64+lr)*32 + g8;

  f32x4 acc[4][4];
  #pragma unroll
  for (int i=0;i<4;i++)
    #pragma unroll
    for (int j=0;j<4;j++) acc[i][j] = (f32x4){0.f,0.f,0.f,0.f};

  auto STAGE = [&](int t, int sofs){
    gll16(gA  + t*32, lds + sofs + dstl);
    gll16(gB0 + t*32, lds + sofs + 4096 + dstl);
    gll16(gB1 + t*32, lds + sofs + 8192 + dstl);
  };

  STAGE(0, 0); STAGE(1, 12288);
  asm volatile("s_waitcnt vmcnt(3)" ::: "memory");
  __builtin_amdgcn_s_barrier();

  int s0 = 0, s1 = 12288, s2 = 24576;
  for (int t=0; t<T; ++t){
    const bool more = (t+2 < T);
    if (more) STAGE(t+2, s2);
    bf16x8 av[4], bv[4];
    #pragma unroll
    for (int i=0;i<4;i++) av[i] = *(const bf16x8*)&lds[s0 + offA0 + i*512];
    #pragma unroll
    for (int j=0;j<4;j++) bv[j] = *(const bf16x8*)&lds[s0 + offB0 + j*512];
    __builtin_amdgcn_s_setprio(1);
    #pragma unroll
    for (int i=0;i<4;i++)
      #pragma unroll
      for (int j=0;j<4;j++)
        acc[i][j] = __builtin_amdgcn_mfma_f32_16x16x32_bf16(av[i], bv[j], acc[i][j], 0,0,0);
    __builtin_amdgcn_s_setprio(0);
    if (more) asm volatile("s_waitcnt vmcnt(3)" ::: "memory");
    else      asm volatile("s_waitcnt vmcnt(0)" ::: "memory");
    __builtin_amdgcn_s_barrier();
    const int tmp = s0; s0 = s1; s1 = s2; s2 = tmp;
  }

  const int rbase = lg*4;
  #pragma unroll
  for (int i=0;i<4;i++){
    #pragma unroll
    for (int j=0;j<4;j++){
      const int col  = n0 + wn*64 + j*16 + lr;
      const int row0 = m0 + wm*64 + i*16 + rbase;
      const float bvl = bias[col];
      #pragma unroll
      for (int r=0;r<4;r++){
        size_t idx = (size_t)(row0+r)*N + col;
        float v = acc[i][j][r] + bvl;
        if (DO_ADD)  v += bf2f(add0[idx]) + bf2f(add1[idx]);
        if (DO_GELU) v = gelu_f(v);
        out[idx] = f2bf(v);
      }
    }
  }
}

// ---------------- adj contraction; FINAL: out_f32 = contraction + tsum(bf16) ----------------
template<int FINAL>
__global__ __launch_bounds__(512) void k_gcn2(
    const u16* __restrict__ G, const float* __restrict__ adj,
    u16* __restrict__ xg,
    const u16* __restrict__ tsum, int b0,
    float* __restrict__ out)
{
  __shared__ __align__(16) float adjp[51*20];
  const int tid = threadIdx.x;
  for (int i=tid; i<1020; i+=512){
    int r=i/20, cl=i%20;
    adjp[i] = (cl<17) ? adj[r*17+cl] : 0.f;
  }
  __syncthreads();

  const int sl  = tid>>7;
  const int l   = tid&127;
  const int c0  = l*4;
  const int bl  = blockIdx.x*4 + sl;

  float acc[JJ][4];
  #pragma unroll
  for (int w=0;w<JJ;w++)
    #pragma unroll
    for (int e=0;e<4;e++) acc[w][e]=0.f;

  const u16* gbase = G + (size_t)bl*JJ*1536 + c0;
  #pragma unroll 3
  for (int kv=0; kv<51; kv++){
    const int k = kv/JJ, v = kv - k*JJ;
    uint2 yu = *(const uint2*)(gbase + (size_t)v*1536 + k*512);
    float y0,y1,y2,y3;
    unpk2(yu.x, y0, y1);
    unpk2(yu.y, y2, y3);
    const f32x4* arow = (const f32x4*)&adjp[kv*20];
    f32x4 a0=arow[0], a1=arow[1], a2=arow[2], a3=arow[3];
    float a16 = adjp[kv*20+16];
    float ar[JJ] = {a0[0],a0[1],a0[2],a0[3], a1[0],a1[1],a1[2],a1[3],
                    a2[0],a2[1],a2[2],a2[3], a3[0],a3[1],a3[2],a3[3], a16};
    #pragma unroll
    for (int w=0;w<JJ;w++){
      acc[w][0] += y0*ar[w];
      acc[w][1] += y1*ar[w];
      acc[w][2] += y2*ar[w];
      acc[w][3] += y3*ar[w];
    }
  }

  if (FINAL==0){
    u16* xo = xg + (size_t)bl*JJ*CC + c0;
    #pragma unroll
    for (int w=0;w<JJ;w++){
      uint2 o;
      o.x = (uint32_t)f2bf(acc[w][0]) | ((uint32_t)f2bf(acc[w][1])<<16);
      o.y = (uint32_t)f2bf(acc[w][2]) | ((uint32_t)f2bf(acc[w][3])<<16);
      *(uint2*)(xo + (size_t)w*CC) = o;
    }
  } else {
    const size_t lb = (size_t)bl*JJ*CC + c0;
    const size_t gb = (size_t)(b0+bl)*JJ*CC + c0;
    #pragma unroll
    for (int w=0;w<JJ;w++){
      uint2 tu = *(const uint2*)(tsum + lb + (size_t)w*CC);
      float t0,t1,t2,t3;
      unpk2(tu.x, t0, t1);
      unpk2(tu.y, t2, t3);
      f32x4 o;
      o[0]=acc[w][0]+t0; o[1]=acc[w][1]+t1;
      o[2]=acc[w][2]+t2; o[3]=acc[w][3]+t3;
      *(f32x4*)(out + gb + (size_t)w*CC) = o;
    }
  }
}

// ---------------- attention over joints: one wave per head, vectorized ----------------
__global__ __launch_bounds__(512) void k_attn(const u16* __restrict__ Gqkv, u16* __restrict__ sga){
  __shared__ __align__(16) u16 qs[8*17*72];
  __shared__ __align__(16) u16 ks_[8*17*72];
  __shared__ __align__(16) float at[8*17*20];
  int b = blockIdx.x, tid = threadIdx.x;
  int h = tid>>6, d = tid&63;
  const u16* base = Gqkv + (size_t)b*JJ*1536;
  float vv[JJ];
  #pragma unroll
  for (int i=0;i<JJ;i++){
    qs [(h*JJ+i)*72 + d] = base[(size_t)i*1536 +        h*64 + d];
    ks_[(h*JJ+i)*72 + d] = base[(size_t)i*1536 +  512 + h*64 + d];
    vv[i] = bf2f(base[(size_t)i*1536 + 1024 + h*64 + d]);
  }
  __syncthreads();
  for (int p=d; p<289; p+=64){
    int i=p/JJ, j=p-i*JJ;
    const u16* qrow = &qs [(h*JJ+i)*72];
    const u16* krow = &ks_[(h*JJ+j)*72];
    float a=0.f;
    #pragma unroll
    for (int t=0;t<8;t++){
      bf16x8 q8 = *(const bf16x8*)&qrow[t*8];
      bf16x8 k8 = *(const bf16x8*)&krow[t*8];
      #pragma unroll
      for (int e=0;e<8;e++) a += (float)q8[e]*(float)k8[e];
    }
    at[(h*JJ+i)*20 + j] = a*0.125f;
  }
  __syncthreads();
  if (d < JJ){
    float* row = &at[(h*JJ+d)*20];
    f32x4 r0=((f32x4*)row)[0], r1=((f32x4*)row)[1], r2=((f32x4*)row)[2], r3=((f32x4*)row)[3];
    float e16=row[16];
    float rv[JJ]={r0[0],r0[1],r0[2],r0[3],r1[0],r1[1],r1[2],r1[3],
                  r2[0],r2[1],r2[2],r2[3],r3[0],r3[1],r3[2],r3[3],e16};
    float mx=-1e30f;
    #pragma unroll
    for (int j=0;j<JJ;j++) mx=fmaxf(mx,rv[j]);
    float sm=0.f;
    #pragma unroll
    for (int j=0;j<JJ;j++){ rv[j]=__builtin_amdgcn_exp2f((rv[j]-mx)*1.44269504089f); sm+=rv[j]; }
    float inv=1.f/sm;
    #pragma unroll
    for (int j=0;j<JJ;j++) row[j]=rv[j]*inv;
  }
  __syncthreads();
  #pragma unroll
  for (int i=0;i<JJ;i++){
    const float* row = &at[(h*JJ+i)*20];
    f32x4 r0=((const f32x4*)row)[0], r1=((const f32x4*)row)[1],
          r2=((const f32x4*)row)[2], r3=((const f32x4*)row)[3];
    float a = r0[0]*vv[0]+r0[1]*vv[1]+r0[2]*vv[2]+r0[3]*vv[3]
            + r1[0]*vv[4]+r1[1]*vv[5]+r1[2]*vv[6]+r1[3]*vv[7]
            + r2[0]*vv[8]+r2[1]*vv[9]+r2[2]*vv[10]+r2[3]*vv[11]
            + r3[0]*vv[12]+r3[1]*vv[13]+r3[2]*vv[14]+r3[3]*vv[15]
            + row[16]*vv[16];
    sga[((size_t)b*JJ+i)*CC + h*64 + d] = f2bf(a);
  }
}

// ---------------- token MLP v4: MFMA (one sample/block, 4 waves, 2 c-passes) ----------------
__global__ __launch_bounds__(256) void k_tok(const u16* __restrict__ Hpw,
    const u16* __restrict__ w1m, const u16* __restrict__ w2m,
    const float* __restrict__ b1, const float* __restrict__ b2,
    u16* __restrict__ h2o){
  __shared__ __align__(16) u16 lds[31488];
  __shared__ float b1s[64], b2s[32];
  const int tid = threadIdx.x, wid = tid>>6, lane = tid&63;
  const int lr = lane&15, lg = lane>>4;
  const int bl = blockIdx.x;
  const f32x4 zz = {0.f,0.f,0.f,0.f};

  for (int i=tid; i<2560; i+=256) lds[26624+i] = w1m[i];
  for (int i=tid; i<2304; i+=256) lds[29184+i] = w2m[i];
  if (tid<64) b1s[tid] = b1[tid];
  if (tid<32) b2s[tid] = (tid<17) ? b2[tid] : 0.f;
  {
    const int base = tid*40;
    lds[base+17]=0; lds[base+18]=0; lds[base+19]=0;
    #pragma unroll
    for (int q=0;q<5;q++) *(uint2*)&lds[base+20+q*4] = (uint2){0u,0u};
  }
  __syncthreads();

  const u16* hp = Hpw + (size_t)bl*JJ*CC;
  u16* op = h2o + (size_t)bl*JJ*CC;

  for (int pass=0; pass<2; ++pass){
    const int cbase = pass*256;
    for (int idx=tid; idx<1088; idx+=256){
      int j = idx>>6, cq = (idx&63)<<2;
      uint2 u = *(const uint2*)(hp + (size_t)j*CC + cbase + cq);
      lds[(cq  )*40 + j] = (u16)(u.x & 0xffffu);
      lds[(cq+1)*40 + j] = (u16)(u.x >> 16);
      lds[(cq+2)*40 + j] = (u16)(u.y & 0xffffu);
      lds[(cq+3)*40 + j] = (u16)(u.y >> 16);
    }
    __syncthreads();

    // ---- fc1 ----
    bf16x8 av1[4];
    #pragma unroll
    for (int mt=0;mt<4;mt++) av1[mt] = *(const bf16x8*)&lds[26624 + (mt*16+lr)*40 + lg*8];
    #pragma unroll
    for (int nt=0;nt<4;nt++){
      const int cl = wid*64 + nt*16 + lr;
      bf16x8 bv = *(const bf16x8*)&lds[cl*40 + lg*8];
      #pragma unroll
      for (int mt=0;mt<4;mt++){
        f32x4 ac = __builtin_amdgcn_mfma_f32_16x16x32_bf16(av1[mt], bv, zz, 0,0,0);
        const int t0 = mt*16 + lg*4;
        float g0 = gelu_f(ac[0] + b1s[t0+0]);
        float g1 = gelu_f(ac[1] + b1s[t0+1]);
        float g2 = gelu_f(ac[2] + b1s[t0+2]);
        float g3 = gelu_f(ac[3] + b1s[t0+3]);
        uint2 pk;
        pk.x = (uint32_t)f2bf(g0) | ((uint32_t)f2bf(g1)<<16);
        pk.y = (uint32_t)f2bf(g2) | ((uint32_t)f2bf(g3)<<16);
        const int gi = (10240 + cl*64 + t0) ^ ((cl&7)<<3);
        *(uint2*)&lds[gi] = pk;
      }
    }
    asm volatile("s_waitcnt lgkmcnt(0)" ::: "memory");
    __builtin_amdgcn_sched_barrier(0);

    // ---- fc2 ----
    bf16x8 av2[2][2];
    #pragma unroll
    for (int mt=0;mt<2;mt++)
      #pragma unroll
      for (int kt=0;kt<2;kt++)
        av2[mt][kt] = *(const bf16x8*)&lds[29184 + (mt*16+lr)*72 + kt*32 + lg*8];
    #pragma unroll
    for (int nt=0;nt<4;nt++){
      const int cl = wid*64 + nt*16 + lr;
      f32x4 a20 = zz, a21 = zz;
      #pragma unroll
      for (int kt=0;kt<2;kt++){
        const int gi = (10240 + cl*64 + kt*32 + lg*8) ^ ((cl&7)<<3);
        bf16x8 bv2 = *(const bf16x8*)&lds[gi];
        a20 = __builtin_amdgcn_mfma_f32_16x16x32_bf16(av2[0][kt], bv2, a20, 0,0,0);
        a21 = __builtin_amdgcn_mfma_f32_16x16x32_bf16(av2[1][kt], bv2, a21, 0,0,0);
      }
      const int c = cbase + cl;
      #pragma unroll
      for (int r=0;r<4;r++){
        const int j = lg*4 + r;
        op[(size_t)j*CC + c] = f2bf(a20[r] + b2s[j]);
      }
      if (lg==0) op[(size_t)16*CC + c] = f2bf(a21[0] + b2s[16]);
    }
    __syncthreads();
  }
}

// ---------------- fuse merged: GN+gelu+tsum (phase A) then LN over C (phase B) ----------
__global__ __launch_bounds__(512) void k_fuse_m(const u16* __restrict__ s,
    const float* __restrict__ x, int b0,
    const float* __restrict__ gfw, const float* __restrict__ gfb,
    const float* __restrict__ n2w, const float* __restrict__ n2b,
    u16* __restrict__ tsum, u16* __restrict__ xn){
  const int tid = threadIdx.x;
  // ---- phase A: GN(gnf)+gelu ; tsum = gelu + x (bf16); 4 samples/block, 4 ch/thread ----
  {
    const int sl  = tid>>7;
    const int l   = tid&127;
    const int c0  = l*4;
    const int bl  = blockIdx.x*4 + sl;

    const u16* sp = s + (size_t)bl*JJ*CC + c0;
    float sv[JJ][4];
    float ss=0.f, sq=0.f;
    #pragma unroll
    for (int j=0;j<JJ;j++){
      uint2 u = *(const uint2*)(sp + (size_t)j*CC);
      unpk2(u.x, sv[j][0], sv[j][1]);
      unpk2(u.y, sv[j][2], sv[j][3]);
      #pragma unroll
      for (int e=0;e<4;e++){ ss += sv[j][e]; sq = fmaf(sv[j][e], sv[j][e], sq); }
    }
    #pragma unroll
    for (int off=8; off; off>>=1){ ss += __shfl_xor(ss,off); sq += __shfl_xor(sq,off); }
    float gm = ss*(1.f/1088.f);
    float gr = rsqrtf(sq*(1.f/1088.f) - gm*gm + 1e-5f);

    f32x4 gw = *(const f32x4*)(gfw + c0);
    f32x4 gb = *(const f32x4*)(gfb + c0);
    const float* xp = x + (size_t)(b0+bl)*JJ*CC + c0;
    u16* tp = tsum + (size_t)bl*JJ*CC + c0;
    #pragma unroll
    for (int j=0;j<JJ;j++){
      f32x4 xv = *(const f32x4*)(xp + (size_t)j*CC);
      float t0 = gelu_f((sv[j][0]-gm)*gr*gw[0] + gb[0]) + xv[0];
      float t1 = gelu_f((sv[j][1]-gm)*gr*gw[1] + gb[1]) + xv[1];
      float t2 = gelu_f((sv[j][2]-gm)*gr*gw[2] + gb[2]) + xv[2];
      float t3 = gelu_f((sv[j][3]-gm)*gr*gw[3] + gb[3]) + xv[3];
      uint2 o;
      o.x = (uint32_t)f2bf(t0) | ((uint32_t)f2bf(t1)<<16);
      o.y = (uint32_t)f2bf(t2) | ((uint32_t)f2bf(t3)<<16);
      *(uint2*)(tp + (size_t)j*CC) = o;
    }
  }
  __syncthreads();   // drains vmcnt: block's tsum writes visible to its reads (L2)
  // ---- phase B: LN over C, one wave per token; block covers 68 tokens ----
  {
    const int wv = tid>>6, lane = tid&63;
    f32x4 w0 = *(const f32x4*)(n2w + lane*8);
    f32x4 w1 = *(const f32x4*)(n2w + lane*8 + 4);
    f32x4 b0v = *(const f32x4*)(n2b + lane*8);
    f32x4 b1v = *(const f32x4*)(n2b + lane*8 + 4);
    float wvv[8] = {w0[0],w0[1],w0[2],w0[3], w1[0],w1[1],w1[2],w1[3]};
    float bvv[8] = {b0v[0],b0v[1],b0v[2],b0v[3], b1v[0],b1v[1],b1v[2],b1v[3]};
    for (int tt = wv; tt < 68; tt += 8){
      const size_t tk = (size_t)blockIdx.x*68 + tt;
      uint4 u = *(const uint4*)(tsum + tk*CC + lane*8);
      float v[8];
      unpk2(u.x, v[0], v[1]);
      unpk2(u.y, v[2], v[3]);
      unpk2(u.z, v[4], v[5]);
      unpk2(u.w, v[6], v[7]);
      float ss=0.f, sq=0.f;
      #pragma unroll
      for (int e=0;e<8;e++){ ss += v[e]; sq = fmaf(v[e], v[e], sq); }
      #pragma unroll
      for (int off=32; off; off>>=1){ ss += __shfl_xor(ss,off); sq += __shfl_xor(sq,off); }
      float mn = ss*(1.f/512.f);
      float r2 = rsqrtf(sq*(1.f/512.f) - mn*mn + 1e-5f);
      u16 o[8];
      #pragma unroll
      for (int e=0;e<8;e++) o[e] = f2bf((v[e]-mn)*r2*wvv[e] + bvv[e]);
      uint4 pk;
      pk.x = (uint32_t)o[0] | ((uint32_t)o[1]<<16);
      pk.y = (uint32_t)o[2] | ((uint32_t)o[3]<<16);
      pk.z = (uint32_t)o[4] | ((uint32_t)o[5]<<16);
      pk.w = (uint32_t)o[6] | ((uint32_t)o[7]<<16);
      *(uint4*)(xn + tk*CC + lane*8) = pk;
    }
  }
}

extern "C" void kernel_launch(void* const* d_in, const int* in_sizes, int n_in,
                              void* d_out, int out_size, void* d_ws, size_t ws_size,
                              hipStream_t stream)
{
  const float* x      = (const float*)d_in[0];
  const float* adj    = (const float*)d_in[1];
  const float* n1w    = (const float*)d_in[2];
  const float* n1b    = (const float*)d_in[3];
  const float* gcn1_w = (const float*)d_in[4];
  const float* gcn1_b = (const float*)d_in[5];
  const float* dw_w   = (const float*)d_in[6];
  const float* dw_b   = (const float*)d_in[7];
  const float* gn1_w  = (const float*)d_in[8];
  const float* gn1_b  = (const float*)d_in[9];
  const float* pw_w   = (const float*)d_in[10];
  const float* pw_b   = (const float*)d_in[11];
  const float* m1w1   = (const float*)d_in[12];
  const float* m1b1   = (const float*)d_in[13];
  const float* m1w2   = (const float*)d_in[14];
  const float* m1b2   = (const float*)d_in[15];
  const float* qkv_w  = (const float*)d_in[16];
  const float* qkv_b  = (const float*)d_in[17];
  const float* proj_w = (const float*)d_in[18];
  const float* proj_b = (const float*)d_in[19];
  const float* gnf_w  = (const float*)d_in[20];
  const float* gnf_b  = (const float*)d_in[21];
  const float* n2w    = (const float*)d_in[22];
  const float* n2b    = (const float*)d_in[23];
  const float* m2w1   = (const float*)d_in[24];
  const float* m2b1   = (const float*)d_in[25];
  const float* m2w2   = (const float*)d_in[26];
  const float* m2b2   = (const float*)d_in[27];
  const float* gcn2_w = (const float*)d_in[28];
  const float* gcn2_b = (const float*)d_in[29];
  float* out = (float*)d_out;

  char* ws = (char*)d_ws;
  const size_t WBYTES = (size_t)3932160*2;
  const size_t TPBYTES = (2560+2304)*2;

  const int cands[5] = {4096,2048,1024,512,256};
  int NB = 0;
  for (int ci=0; ci<5; ci++){
    size_t need = WBYTES + TPBYTES + (size_t)cands[ci]*JJ*2*(1536 + 4*512);
    if (need <= ws_size){ NB = cands[ci]; break; }
  }
  if (NB == 0) return;

  u16* wb = (u16*)ws;
  u16* w1m = (u16*)(ws + WBYTES);
  u16* w2m = w1m + 2560;
  char* p = ws + WBYTES + TPBYTES;
  const size_t SZ_BIGc = (size_t)NB*JJ*1536*2;
  const size_t SZTc    = (size_t)NB*JJ*512*2;
  u16* big = (u16*)p;               p += SZ_BIGc;
  u16* t0  = (u16*)p;               p += SZTc;   // xc -> Hpw -> s -> m2
  u16* t1  = (u16*)p;               p += SZTc;   // hgn -> h2
  u16* t2  = (u16*)p;               p += SZTc;   // xg -> xn
  u16* t3  = (u16*)p;                            // sga -> tsum

  u16 *wg1=wb, *wqkv=wb+786432, *wpw=wb+1572864, *wproj=wb+1835008,
      *wm1=wb+2097152, *wm2=wb+2621440, *wg2=wb+3145728;

  k_cvt7<<<(3932160+255)/256,256,0,stream>>>(gcn1_w,qkv_w,pw_w,proj_w,m2w1,m2w2,gcn2_w,wb);
  k_tokprep<<<19,256,0,stream>>>(m1w1,m1w2,w1m,w2m);

  const int M2 = NB*JJ;
  const int MT = M2/128;
  for (int b0 = 0; b0 < BB; b0 += NB){
    k_pre<<<NB/4,512,0,stream>>>(x,b0,n1w,n1b,dw_w,dw_b,gn1_w,gn1_b, t0/*xc*/, t1/*hgn*/);
    // GCN1 (N=1536 -> NXT=6)
    gemm_r5<0,0><<<MT*6,512,0,stream>>>(t0,wg1,gcn1_b,big,nullptr,nullptr,M2,1536,512,6);
    k_gcn2<0><<<NB/4,512,0,stream>>>(big,adj,t2/*xg*/,nullptr,0,nullptr);
    // QKV + attention
    gemm_r5<0,0><<<MT*6,512,0,stream>>>(t0,wqkv,qkv_b,big,nullptr,nullptr,M2,1536,512,6);
    k_attn<<<NB,512,0,stream>>>(big,t3/*sga*/);
    // pw + token MLP  (xc dead -> t0 reused for Hpw)
    gemm_r5<0,0><<<MT*2,512,0,stream>>>(t1,wpw,pw_b,t0/*Hpw*/,nullptr,nullptr,M2,512,512,2);
    k_tok<<<NB,256,0,stream>>>(t0,w1m,w2m,m1b1,m1b2,t1/*h2*/);
    // proj + branch merge: s = proj(sga)+b + xg + h2   (sga consumed -> t3 free)
    gemm_r5<0,1><<<MT*2,512,0,stream>>>(t3,wproj,proj_b,t0/*s*/,t2,t1,M2,512,512,2);
    // GN(gnf)+gelu ; tsum=rc+x -> t3 ; LN2(tsum) -> xn (t2)   [merged]
    k_fuse_m<<<NB/4,512,0,stream>>>(t0,x,b0,gnf_w,gnf_b,n2w,n2b,t3/*tsum*/,t2/*xn*/);
    // MLP2
    gemm_r5<1,0><<<MT*4,512,0,stream>>>(t2,wm1,m2b1,big/*m*/,nullptr,nullptr,M2,1024,512,4);
    gemm_r5<0,0><<<MT*2,512,0,stream>>>(big,wm2,m2b2,t0/*m2*/,nullptr,nullptr,M2,512,1024,2);
    // GCN2
    gemm_r5<0,0><<<MT*6,512,0,stream>>>(t0,wg2,gcn2_b,big/*G2*/,nullptr,nullptr,M2,1536,512,6);
    k_gcn2<1><<<NB/4,512,0,stream>>>(big,adj,nullptr,t3/*tsum*/,b0,out);
  }
}

// Round 19
// 1256.171 us; speedup vs baseline: 1.0652x; 1.0135x over previous
//
#include <hip/hip_runtime.h>
#include <stdint.h>

#define BB 4096
#define JJ 17
#define CC 512

typedef unsigned short u16;
typedef __bf16 bf16x8 __attribute__((ext_vector_type(8)));
typedef float  f32x4  __attribute__((ext_vector_type(4)));

__device__ __forceinline__ float bf2f(u16 u){ return __uint_as_float(((uint32_t)u)<<16); }
__device__ __forceinline__ u16 f2bf(float f){
  uint32_t u = __float_as_uint(f);
  u += 0x7fffu + ((u>>16)&1u);           // round-to-nearest-even
  return (u16)(u>>16);
}
__device__ __forceinline__ void unpk2(uint32_t u, float& lo, float& hi){
  lo = __uint_as_float(u<<16);
  hi = __uint_as_float(u & 0xffff0000u);
}
// tanh-approx GELU: max |err| vs exact-erf ~3e-3 (threshold is 0.166)
__device__ __forceinline__ float gelu_f(float x){
  float x2 = x*x;
  float y2 = x*fmaf(0.0713548162726f, x2, 1.59576912161f);
  float ey = __builtin_amdgcn_exp2f(y2*1.44269504089f);
  return fmaf(-x, __builtin_amdgcn_rcpf(ey+1.f), x);
}
__device__ __forceinline__ void gll16(const void* g, void* l){
  __builtin_amdgcn_global_load_lds(
      (const __attribute__((address_space(1))) void*)g,
      (__attribute__((address_space(3))) void*)l, 16, 0, 0);
}

// ---------------- merged weight f32 -> bf16 convert (7 ranges, 1 launch) ----------------
__global__ void k_cvt7(const float* __restrict__ s0,const float* __restrict__ s1,
                       const float* __restrict__ s2,const float* __restrict__ s3,
                       const float* __restrict__ s4,const float* __restrict__ s5,
                       const float* __restrict__ s6, u16* __restrict__ out){
  int i = blockIdx.x*blockDim.x + threadIdx.x;
  if (i >= 3932160) return;
  const float* src; int off;
  if      (i < 786432)  { src=s0; off=0; }
  else if (i < 1572864) { src=s1; off=786432; }
  else if (i < 1835008) { src=s2; off=1572864; }
  else if (i < 2097152) { src=s3; off=1835008; }
  else if (i < 2621440) { src=s4; off=2097152; }
  else if (i < 3145728) { src=s5; off=2621440; }
  else                  { src=s6; off=3145728; }
  out[i] = f2bf(src[i-off]);
}

// ---------------- token-MLP weight prep: padded bf16 [64][40] and [32][72] ----------------
__global__ void k_tokprep(const float* __restrict__ w1, const float* __restrict__ w2,
                          u16* __restrict__ w1m, u16* __restrict__ w2m){
  int i = blockIdx.x*blockDim.x + threadIdx.x;
  if (i < 2560){ int t=i/40, j=i%40; w1m[i] = (j<17) ? f2bf(w1[t*17+j]) : (u16)0; }
  int k = i - 2560;
  if (k >= 0 && k < 2304){ int j=k/72, t=k%72; w2m[k] = (j<17 && t<64) ? f2bf(w2[j*64+t]) : (u16)0; }
}

// ---------------- pre: LN(over J) + dwconv + GN1 + gelu (r16 champion version) ----------
__global__ __launch_bounds__(512) void k_pre(
    const float* __restrict__ x, int b0,
    const float* __restrict__ n1w, const float* __restrict__ n1b,
    const float* __restrict__ dww, const float* __restrict__ dwb,
    const float* __restrict__ gn1w, const float* __restrict__ gn1b,
    u16* __restrict__ xc, u16* __restrict__ hgn)
{
  int b = blockIdx.x, c = threadIdx.x;
  const float* xp = x + (size_t)(b0+b)*JJ*CC + c;
  float v[JJ]; float s = 0.f;
  #pragma unroll
  for (int j=0;j<JJ;j++){ v[j] = xp[(size_t)j*CC]; s += v[j]; }
  float mn = s*(1.f/JJ); float var = 0.f;
  #pragma unroll
  for (int j=0;j<JJ;j++){ float d=v[j]-mn; var += d*d; }
  float rr = rsqrtf(var*(1.f/JJ)+1e-5f);
  float xcv[JJ];
  #pragma unroll
  for (int j=0;j<JJ;j++) xcv[j] = (v[j]-mn)*rr*n1w[j] + n1b[j];
  u16* xo = xc + (size_t)b*JJ*CC + c;
  #pragma unroll
  for (int j=0;j<JJ;j++) xo[(size_t)j*CC] = f2bf(xcv[j]);
  float w0=dww[c*3+0], w1=dww[c*3+1], w2=dww[c*3+2], db=dwb[c];
  float h[JJ];
  #pragma unroll
  for (int j=0;j<JJ;j++){
    float a = db + w1*xcv[j];
    if (j>0)    a += w0*xcv[j-1];
    if (j<JJ-1) a += w2*xcv[j+1];
    h[j] = a;
  }
  float ss=0.f, sq=0.f;
  #pragma unroll
  for (int j=0;j<JJ;j++){ ss += h[j]; sq += h[j]*h[j]; }
  for (int off=32; off; off>>=1){ ss += __shfl_xor(ss,off); sq += __shfl_xor(sq,off); }
  float gm = ss*(1.f/(64.f*JJ));
  float gr = rsqrtf(sq*(1.f/(64.f*JJ)) - gm*gm + 1e-5f);
  float gw = gn1w[c], gb = gn1b[c];
  u16* ho = hgn + (size_t)b*JJ*CC + c;
  #pragma unroll
  for (int j=0;j<JJ;j++){
    float t = (h[j]-gm)*gr*gw + gb;
    ho[(size_t)j*CC] = f2bf(gelu_f(t));
  }
}

// ---------------- 128x256x32 ring-3 counted-vmcnt MFMA GEMM, 8 waves (champion) ----------
template<int DO_GELU, int DO_ADD>
__global__ __launch_bounds__(512,4) void gemm_r5(
    const u16* __restrict__ A, const u16* __restrict__ W, const float* __restrict__ bias,
    u16* __restrict__ out, const u16* __restrict__ add0, const u16* __restrict__ add1,
    int M, int N, int K, int NXT)
{
  __shared__ __align__(16) u16 lds[36864];   // 3 x 12288 u16 (24KB slots)
  const int tid = threadIdx.x;
  const int wid = tid>>6, lane = tid&63;

  const int nwg = gridDim.x;
  const int q8 = nwg>>3, r8 = nwg&7;
  const int xcd = blockIdx.x & 7, sub = blockIdx.x >> 3;
  const int wg = (xcd<r8 ? xcd*(q8+1) : r8*(q8+1)+(xcd-r8)*q8) + sub;
  const int n0 = (wg % NXT)*256;
  const int m0 = (wg / NXT)*128;

  const int wm = wid>>2, wn = wid&3;      // 2M x 4N waves, 64x64 out per wave
  const int lr = lane&15, lg = lane>>4;
  const int T  = K>>5;

  const int agsw = ((tid&3) ^ ((tid>>3)&3))<<3;
  const u16* gA  = A + (size_t)(m0 + (tid>>2))*K + agsw;
  const u16* gB0 = W + (size_t)(n0 + (tid>>2))*K + agsw;
  const u16* gB1 = W + (size_t)(n0 + 128 + (tid>>2))*K + agsw;
  const int dstl = tid*8;

  const int g8 = (lg ^ ((lr>>1)&3))<<3;
  const int offA0 = (wm*64+lr)*32 + g8;
  const int offB0 = 4096 + (wn*64+lr)*32 + g8;

  f32x4 acc[4][4];
  #pragma unroll
  for (int i=0;i<4;i++)
    #pragma unroll
    for (int j=0;j<4;j++) acc[i][j] = (f32x4){0.f,0.f,0.f,0.f};

  auto STAGE = [&](int t, int sofs){
    gll16(gA  + t*32, lds + sofs + dstl);
    gll16(gB0 + t*32, lds + sofs + 4096 + dstl);
    gll16(gB1 + t*32, lds + sofs + 8192 + dstl);
  };

  STAGE(0, 0); STAGE(1, 12288);
  asm volatile("s_waitcnt vmcnt(3)" ::: "memory");
  __builtin_amdgcn_s_barrier();

  int s0 = 0, s1 = 12288, s2 = 24576;
  for (int t=0; t<T; ++t){
    const bool more = (t+2 < T);
    if (more) STAGE(t+2, s2);
    bf16x8 av[4], bv[4];
    #pragma unroll
    for (int i=0;i<4;i++) av[i] = *(const bf16x8*)&lds[s0 + offA0 + i*512];
    #pragma unroll
    for (int j=0;j<4;j++) bv[j] = *(const bf16x8*)&lds[s0 + offB0 + j*512];
    __builtin_amdgcn_s_setprio(1);
    #pragma unroll
    for (int i=0;i<4;i++)
      #pragma unroll
      for (int j=0;j<4;j++)
        acc[i][j] = __builtin_amdgcn_mfma_f32_16x16x32_bf16(av[i], bv[j], acc[i][j], 0,0,0);
    __builtin_amdgcn_s_setprio(0);
    if (more) asm volatile("s_waitcnt vmcnt(3)" ::: "memory");
    else      asm volatile("s_waitcnt vmcnt(0)" ::: "memory");
    __builtin_amdgcn_s_barrier();
    const int tmp = s0; s0 = s1; s1 = s2; s2 = tmp;
  }

  const int rbase = lg*4;
  #pragma unroll
  for (int i=0;i<4;i++){
    #pragma unroll
    for (int j=0;j<4;j++){
      const int col  = n0 + wn*64 + j*16 + lr;
      const int row0 = m0 + wm*64 + i*16 + rbase;
      const float bvl = bias[col];
      #pragma unroll
      for (int r=0;r<4;r++){
        size_t idx = (size_t)(row0+r)*N + col;
        float v = acc[i][j][r] + bvl;
        if (DO_ADD)  v += bf2f(add0[idx]) + bf2f(add1[idx]);
        if (DO_GELU) v = gelu_f(v);
        out[idx] = f2bf(v);
      }
    }
  }
}

// ---------------- adj contraction; FINAL: out_f32 = contraction + tsum(bf16) ----------------
template<int FINAL>
__global__ __launch_bounds__(512) void k_gcn2(
    const u16* __restrict__ G, const float* __restrict__ adj,
    u16* __restrict__ xg,
    const u16* __restrict__ tsum, int b0,
    float* __restrict__ out)
{
  __shared__ __align__(16) float adjp[51*20];
  const int tid = threadIdx.x;
  for (int i=tid; i<1020; i+=512){
    int r=i/20, cl=i%20;
    adjp[i] = (cl<17) ? adj[r*17+cl] : 0.f;
  }
  __syncthreads();

  const int sl  = tid>>7;
  const int l   = tid&127;
  const int c0  = l*4;
  const int bl  = blockIdx.x*4 + sl;

  float acc[JJ][4];
  #pragma unroll
  for (int w=0;w<JJ;w++)
    #pragma unroll
    for (int e=0;e<4;e++) acc[w][e]=0.f;

  const u16* gbase = G + (size_t)bl*JJ*1536 + c0;
  #pragma unroll 3
  for (int kv=0; kv<51; kv++){
    const int k = kv/JJ, v = kv - k*JJ;
    uint2 yu = *(const uint2*)(gbase + (size_t)v*1536 + k*512);
    float y0,y1,y2,y3;
    unpk2(yu.x, y0, y1);
    unpk2(yu.y, y2, y3);
    const f32x4* arow = (const f32x4*)&adjp[kv*20];
    f32x4 a0=arow[0], a1=arow[1], a2=arow[2], a3=arow[3];
    float a16 = adjp[kv*20+16];
    float ar[JJ] = {a0[0],a0[1],a0[2],a0[3], a1[0],a1[1],a1[2],a1[3],
                    a2[0],a2[1],a2[2],a2[3], a3[0],a3[1],a3[2],a3[3], a16};
    #pragma unroll
    for (int w=0;w<JJ;w++){
      acc[w][0] += y0*ar[w];
      acc[w][1] += y1*ar[w];
      acc[w][2] += y2*ar[w];
      acc[w][3] += y3*ar[w];
    }
  }

  if (FINAL==0){
    u16* xo = xg + (size_t)bl*JJ*CC + c0;
    #pragma unroll
    for (int w=0;w<JJ;w++){
      uint2 o;
      o.x = (uint32_t)f2bf(acc[w][0]) | ((uint32_t)f2bf(acc[w][1])<<16);
      o.y = (uint32_t)f2bf(acc[w][2]) | ((uint32_t)f2bf(acc[w][3])<<16);
      *(uint2*)(xo + (size_t)w*CC) = o;
    }
  } else {
    const size_t lb = (size_t)bl*JJ*CC + c0;
    const size_t gb = (size_t)(b0+bl)*JJ*CC + c0;
    #pragma unroll
    for (int w=0;w<JJ;w++){
      uint2 tu = *(const uint2*)(tsum + lb + (size_t)w*CC);
      float t0,t1,t2,t3;
      unpk2(tu.x, t0, t1);
      unpk2(tu.y, t2, t3);
      f32x4 o;
      o[0]=acc[w][0]+t0; o[1]=acc[w][1]+t1;
      o[2]=acc[w][2]+t2; o[3]=acc[w][3]+t3;
      *(f32x4*)(out + gb + (size_t)w*CC) = o;
    }
  }
}

// ---------------- attention over joints: one wave per head, vectorized ----------------
__global__ __launch_bounds__(512) void k_attn(const u16* __restrict__ Gqkv, u16* __restrict__ sga){
  __shared__ __align__(16) u16 qs[8*17*72];
  __shared__ __align__(16) u16 ks_[8*17*72];
  __shared__ __align__(16) float at[8*17*20];
  int b = blockIdx.x, tid = threadIdx.x;
  int h = tid>>6, d = tid&63;
  const u16* base = Gqkv + (size_t)b*JJ*1536;
  float vv[JJ];
  #pragma unroll
  for (int i=0;i<JJ;i++){
    qs [(h*JJ+i)*72 + d] = base[(size_t)i*1536 +        h*64 + d];
    ks_[(h*JJ+i)*72 + d] = base[(size_t)i*1536 +  512 + h*64 + d];
    vv[i] = bf2f(base[(size_t)i*1536 + 1024 + h*64 + d]);
  }
  __syncthreads();
  for (int p=d; p<289; p+=64){
    int i=p/JJ, j=p-i*JJ;
    const u16* qrow = &qs [(h*JJ+i)*72];
    const u16* krow = &ks_[(h*JJ+j)*72];
    float a=0.f;
    #pragma unroll
    for (int t=0;t<8;t++){
      bf16x8 q8 = *(const bf16x8*)&qrow[t*8];
      bf16x8 k8 = *(const bf16x8*)&krow[t*8];
      #pragma unroll
      for (int e=0;e<8;e++) a += (float)q8[e]*(float)k8[e];
    }
    at[(h*JJ+i)*20 + j] = a*0.125f;
  }
  __syncthreads();
  if (d < JJ){
    float* row = &at[(h*JJ+d)*20];
    f32x4 r0=((f32x4*)row)[0], r1=((f32x4*)row)[1], r2=((f32x4*)row)[2], r3=((f32x4*)row)[3];
    float e16=row[16];
    float rv[JJ]={r0[0],r0[1],r0[2],r0[3],r1[0],r1[1],r1[2],r1[3],
                  r2[0],r2[1],r2[2],r2[3],r3[0],r3[1],r3[2],r3[3],e16};
    float mx=-1e30f;
    #pragma unroll
    for (int j=0;j<JJ;j++) mx=fmaxf(mx,rv[j]);
    float sm=0.f;
    #pragma unroll
    for (int j=0;j<JJ;j++){ rv[j]=__builtin_amdgcn_exp2f((rv[j]-mx)*1.44269504089f); sm+=rv[j]; }
    float inv=1.f/sm;
    #pragma unroll
    for (int j=0;j<JJ;j++) row[j]=rv[j]*inv;
  }
  __syncthreads();
  #pragma unroll
  for (int i=0;i<JJ;i++){
    const float* row = &at[(h*JJ+i)*20];
    f32x4 r0=((const f32x4*)row)[0], r1=((const f32x4*)row)[1],
          r2=((const f32x4*)row)[2], r3=((const f32x4*)row)[3];
    float a = r0[0]*vv[0]+r0[1]*vv[1]+r0[2]*vv[2]+r0[3]*vv[3]
            + r1[0]*vv[4]+r1[1]*vv[5]+r1[2]*vv[6]+r1[3]*vv[7]
            + r2[0]*vv[8]+r2[1]*vv[9]+r2[2]*vv[10]+r2[3]*vv[11]
            + r3[0]*vv[12]+r3[1]*vv[13]+r3[2]*vv[14]+r3[3]*vv[15]
            + row[16]*vv[16];
    sga[((size_t)b*JJ+i)*CC + h*64 + d] = f2bf(a);
  }
}

// ---------------- token MLP v4: MFMA (one sample/block, 4 waves, 2 c-passes) ----------------
__global__ __launch_bounds__(256) void k_tok(const u16* __restrict__ Hpw,
    const u16* __restrict__ w1m, const u16* __restrict__ w2m,
    const float* __restrict__ b1, const float* __restrict__ b2,
    u16* __restrict__ h2o){
  __shared__ __align__(16) u16 lds[31488];
  __shared__ float b1s[64], b2s[32];
  const int tid = threadIdx.x, wid = tid>>6, lane = tid&63;
  const int lr = lane&15, lg = lane>>4;
  const int bl = blockIdx.x;
  const f32x4 zz = {0.f,0.f,0.f,0.f};

  for (int i=tid; i<2560; i+=256) lds[26624+i] = w1m[i];
  for (int i=tid; i<2304; i+=256) lds[29184+i] = w2m[i];
  if (tid<64) b1s[tid] = b1[tid];
  if (tid<32) b2s[tid] = (tid<17) ? b2[tid] : 0.f;
  {
    const int base = tid*40;
    lds[base+17]=0; lds[base+18]=0; lds[base+19]=0;
    #pragma unroll
    for (int q=0;q<5;q++) *(uint2*)&lds[base+20+q*4] = (uint2){0u,0u};
  }
  __syncthreads();

  const u16* hp = Hpw + (size_t)bl*JJ*CC;
  u16* op = h2o + (size_t)bl*JJ*CC;

  for (int pass=0; pass<2; ++pass){
    const int cbase = pass*256;
    for (int idx=tid; idx<1088; idx+=256){
      int j = idx>>6, cq = (idx&63)<<2;
      uint2 u = *(const uint2*)(hp + (size_t)j*CC + cbase + cq);
      lds[(cq  )*40 + j] = (u16)(u.x & 0xffffu);
      lds[(cq+1)*40 + j] = (u16)(u.x >> 16);
      lds[(cq+2)*40 + j] = (u16)(u.y & 0xffffu);
      lds[(cq+3)*40 + j] = (u16)(u.y >> 16);
    }
    __syncthreads();

    // ---- fc1 ----
    bf16x8 av1[4];
    #pragma unroll
    for (int mt=0;mt<4;mt++) av1[mt] = *(const bf16x8*)&lds[26624 + (mt*16+lr)*40 + lg*8];
    #pragma unroll
    for (int nt=0;nt<4;nt++){
      const int cl = wid*64 + nt*16 + lr;
      bf16x8 bv = *(const bf16x8*)&lds[cl*40 + lg*8];
      #pragma unroll
      for (int mt=0;mt<4;mt++){
        f32x4 ac = __builtin_amdgcn_mfma_f32_16x16x32_bf16(av1[mt], bv, zz, 0,0,0);
        const int t0 = mt*16 + lg*4;
        float g0 = gelu_f(ac[0] + b1s[t0+0]);
        float g1 = gelu_f(ac[1] + b1s[t0+1]);
        float g2 = gelu_f(ac[2] + b1s[t0+2]);
        float g3 = gelu_f(ac[3] + b1s[t0+3]);
        uint2 pk;
        pk.x = (uint32_t)f2bf(g0) | ((uint32_t)f2bf(g1)<<16);
        pk.y = (uint32_t)f2bf(g2) | ((uint32_t)f2bf(g3)<<16);
        const int gi = (10240 + cl*64 + t0) ^ ((cl&7)<<3);
        *(uint2*)&lds[gi] = pk;
      }
    }
    asm volatile("s_waitcnt lgkmcnt(0)" ::: "memory");
    __builtin_amdgcn_sched_barrier(0);

    // ---- fc2 ----
    bf16x8 av2[2][2];
    #pragma unroll
    for (int mt=0;mt<2;mt++)
      #pragma unroll
      for (int kt=0;kt<2;kt++)
        av2[mt][kt] = *(const bf16x8*)&lds[29184 + (mt*16+lr)*72 + kt*32 + lg*8];
    #pragma unroll
    for (int nt=0;nt<4;nt++){
      const int cl = wid*64 + nt*16 + lr;
      f32x4 a20 = zz, a21 = zz;
      #pragma unroll
      for (int kt=0;kt<2;kt++){
        const int gi = (10240 + cl*64 + kt*32 + lg*8) ^ ((cl&7)<<3);
        bf16x8 bv2 = *(const bf16x8*)&lds[gi];
        a20 = __builtin_amdgcn_mfma_f32_16x16x32_bf16(av2[0][kt], bv2, a20, 0,0,0);
        a21 = __builtin_amdgcn_mfma_f32_16x16x32_bf16(av2[1][kt], bv2, a21, 0,0,0);
      }
      const int c = cbase + cl;
      #pragma unroll
      for (int r=0;r<4;r++){
        const int j = lg*4 + r;
        op[(size_t)j*CC + c] = f2bf(a20[r] + b2s[j]);
      }
      if (lg==0) op[(size_t)16*CC + c] = f2bf(a21[0] + b2s[16]);
    }
    __syncthreads();
  }
}

// ---------------- fuse part A: GN(gnf)+gelu ; tsum = gelu + x (bf16), 4ch/thread ----------
__global__ __launch_bounds__(512) void k_fuse_a(const u16* __restrict__ s,
    const float* __restrict__ x, int b0,
    const float* __restrict__ gfw, const float* __restrict__ gfb,
    u16* __restrict__ tsum){
  const int tid = threadIdx.x;
  const int sl  = tid>>7;
  const int l   = tid&127;
  const int c0  = l*4;
  const int bl  = blockIdx.x*4 + sl;

  const u16* sp = s + (size_t)bl*JJ*CC + c0;
  float sv[JJ][4];
  float ss=0.f, sq=0.f;
  #pragma unroll
  for (int j=0;j<JJ;j++){
    uint2 u = *(const uint2*)(sp + (size_t)j*CC);
    unpk2(u.x, sv[j][0], sv[j][1]);
    unpk2(u.y, sv[j][2], sv[j][3]);
    #pragma unroll
    for (int e=0;e<4;e++){ ss += sv[j][e]; sq = fmaf(sv[j][e], sv[j][e], sq); }
  }
  #pragma unroll
  for (int off=8; off; off>>=1){ ss += __shfl_xor(ss,off); sq += __shfl_xor(sq,off); }
  float gm = ss*(1.f/1088.f);
  float gr = rsqrtf(sq*(1.f/1088.f) - gm*gm + 1e-5f);

  f32x4 gw = *(const f32x4*)(gfw + c0);
  f32x4 gb = *(const f32x4*)(gfb + c0);
  const float* xp = x + (size_t)(b0+bl)*JJ*CC + c0;
  u16* tp = tsum + (size_t)bl*JJ*CC + c0;
  #pragma unroll
  for (int j=0;j<JJ;j++){
    f32x4 xv = *(const f32x4*)(xp + (size_t)j*CC);
    float t0 = gelu_f((sv[j][0]-gm)*gr*gw[0] + gb[0]) + xv[0];
    float t1 = gelu_f((sv[j][1]-gm)*gr*gw[1] + gb[1]) + xv[1];
    float t2 = gelu_f((sv[j][2]-gm)*gr*gw[2] + gb[2]) + xv[2];
    float t3 = gelu_f((sv[j][3]-gm)*gr*gw[3] + gb[3]) + xv[3];
    uint2 o;
    o.x = (uint32_t)f2bf(t0) | ((uint32_t)f2bf(t1)<<16);
    o.y = (uint32_t)f2bf(t2) | ((uint32_t)f2bf(t3)<<16);
    *(uint2*)(tp + (size_t)j*CC) = o;
  }
}

// ---------------- fuse part B: LN over C, one wave per token ----------------
__global__ __launch_bounds__(512) void k_ln(const u16* __restrict__ tsum,
    const float* __restrict__ n2w, const float* __restrict__ n2b,
    u16* __restrict__ xn){
  const int wid = threadIdx.x>>6, lane = threadIdx.x&63;
  const size_t tk = (size_t)blockIdx.x*8 + wid;
  const u16* tp = tsum + tk*CC + lane*8;
  uint4 u = *(const uint4*)tp;
  float v[8];
  unpk2(u.x, v[0], v[1]);
  unpk2(u.y, v[2], v[3]);
  unpk2(u.z, v[4], v[5]);
  unpk2(u.w, v[6], v[7]);
  float ss=0.f, sq=0.f;
  #pragma unroll
  for (int e=0;e<8;e++){ ss += v[e]; sq = fmaf(v[e], v[e], sq); }
  #pragma unroll
  for (int off=32; off; off>>=1){ ss += __shfl_xor(ss,off); sq += __shfl_xor(sq,off); }
  float mn = ss*(1.f/512.f);
  float r2 = rsqrtf(sq*(1.f/512.f) - mn*mn + 1e-5f);
  f32x4 w0 = *(const f32x4*)(n2w + lane*8);
  f32x4 w1 = *(const f32x4*)(n2w + lane*8 + 4);
  f32x4 b0 = *(const f32x4*)(n2b + lane*8);
  f32x4 b1 = *(const f32x4*)(n2b + lane*8 + 4);
  float wv[8] = {w0[0],w0[1],w0[2],w0[3], w1[0],w1[1],w1[2],w1[3]};
  float bv[8] = {b0[0],b0[1],b0[2],b0[3], b1[0],b1[1],b1[2],b1[3]};
  u16 o[8];
  #pragma unroll
  for (int e=0;e<8;e++) o[e] = f2bf((v[e]-mn)*r2*wv[e] + bv[e]);
  uint4 pk;
  pk.x = (uint32_t)o[0] | ((uint32_t)o[1]<<16);
  pk.y = (uint32_t)o[2] | ((uint32_t)o[3]<<16);
  pk.z = (uint32_t)o[4] | ((uint32_t)o[5]<<16);
  pk.w = (uint32_t)o[6] | ((uint32_t)o[7]<<16);
  *(uint4*)(xn + tk*CC + lane*8) = pk;
}

extern "C" void kernel_launch(void* const* d_in, const int* in_sizes, int n_in,
                              void* d_out, int out_size, void* d_ws, size_t ws_size,
                              hipStream_t stream)
{
  const float* x      = (const float*)d_in[0];
  const float* adj    = (const float*)d_in[1];
  const float* n1w    = (const float*)d_in[2];
  const float* n1b    = (const float*)d_in[3];
  const float* gcn1_w = (const float*)d_in[4];
  const float* gcn1_b = (const float*)d_in[5];
  const float* dw_w   = (const float*)d_in[6];
  const float* dw_b   = (const float*)d_in[7];
  const float* gn1_w  = (const float*)d_in[8];
  const float* gn1_b  = (const float*)d_in[9];
  const float* pw_w   = (const float*)d_in[10];
  const float* pw_b   = (const float*)d_in[11];
  const float* m1w1   = (const float*)d_in[12];
  const float* m1b1   = (const float*)d_in[13];
  const float* m1w2   = (const float*)d_in[14];
  const float* m1b2   = (const float*)d_in[15];
  const float* qkv_w  = (const float*)d_in[16];
  const float* qkv_b  = (const float*)d_in[17];
  const float* proj_w = (const float*)d_in[18];
  const float* proj_b = (const float*)d_in[19];
  const float* gnf_w  = (const float*)d_in[20];
  const float* gnf_b  = (const float*)d_in[21];
  const float* n2w    = (const float*)d_in[22];
  const float* n2b    = (const float*)d_in[23];
  const float* m2w1   = (const float*)d_in[24];
  const float* m2b1   = (const float*)d_in[25];
  const float* m2w2   = (const float*)d_in[26];
  const float* m2b2   = (const float*)d_in[27];
  const float* gcn2_w = (const float*)d_in[28];
  const float* gcn2_b = (const float*)d_in[29];
  float* out = (float*)d_out;

  char* ws = (char*)d_ws;
  const size_t WBYTES = (size_t)3932160*2;
  const size_t TPBYTES = (2560+2304)*2;

  const int cands[5] = {4096,2048,1024,512,256};
  int NB = 0;
  for (int ci=0; ci<5; ci++){
    size_t need = WBYTES + TPBYTES + (size_t)cands[ci]*JJ*2*(1536 + 4*512);
    if (need <= ws_size){ NB = cands[ci]; break; }
  }
  if (NB == 0) return;

  u16* wb = (u16*)ws;
  u16* w1m = (u16*)(ws + WBYTES);
  u16* w2m = w1m + 2560;
  char* p = ws + WBYTES + TPBYTES;
  const size_t SZ_BIGc = (size_t)NB*JJ*1536*2;
  const size_t SZTc    = (size_t)NB*JJ*512*2;
  u16* big = (u16*)p;               p += SZ_BIGc;
  u16* t0  = (u16*)p;               p += SZTc;   // xc -> Hpw -> s -> m2
  u16* t1  = (u16*)p;               p += SZTc;   // hgn -> h2
  u16* t2  = (u16*)p;               p += SZTc;   // xg -> xn
  u16* t3  = (u16*)p;                            // sga -> tsum

  u16 *wg1=wb, *wqkv=wb+786432, *wpw=wb+1572864, *wproj=wb+1835008,
      *wm1=wb+2097152, *wm2=wb+2621440, *wg2=wb+3145728;

  k_cvt7<<<(3932160+255)/256,256,0,stream>>>(gcn1_w,qkv_w,pw_w,proj_w,m2w1,m2w2,gcn2_w,wb);
  k_tokprep<<<19,256,0,stream>>>(m1w1,m1w2,w1m,w2m);

  const int M2 = NB*JJ;
  const int MT = M2/128;
  for (int b0 = 0; b0 < BB; b0 += NB){
    k_pre<<<NB,512,0,stream>>>(x,b0,n1w,n1b,dw_w,dw_b,gn1_w,gn1_b, t0/*xc*/, t1/*hgn*/);
    // GCN1 (N=1536 -> NXT=6)
    gemm_r5<0,0><<<MT*6,512,0,stream>>>(t0,wg1,gcn1_b,big,nullptr,nullptr,M2,1536,512,6);
    k_gcn2<0><<<NB/4,512,0,stream>>>(big,adj,t2/*xg*/,nullptr,0,nullptr);
    // QKV + attention
    gemm_r5<0,0><<<MT*6,512,0,stream>>>(t0,wqkv,qkv_b,big,nullptr,nullptr,M2,1536,512,6);
    k_attn<<<NB,512,0,stream>>>(big,t3/*sga*/);
    // pw + token MLP  (xc dead -> t0 reused for Hpw)
    gemm_r5<0,0><<<MT*2,512,0,stream>>>(t1,wpw,pw_b,t0/*Hpw*/,nullptr,nullptr,M2,512,512,2);
    k_tok<<<NB,256,0,stream>>>(t0,w1m,w2m,m1b1,m1b2,t1/*h2*/);
    // proj + branch merge: s = proj(sga)+b + xg + h2   (sga consumed -> t3 free)
    gemm_r5<0,1><<<MT*2,512,0,stream>>>(t3,wproj,proj_b,t0/*s*/,t2,t1,M2,512,512,2);
    // GN(gnf)+gelu ; tsum=rc+x -> t3 ; LN2(tsum) -> xn (t2)
    k_fuse_a<<<NB/4,512,0,stream>>>(t0,x,b0,gnf_w,gnf_b,t3/*tsum*/);
    k_ln<<<M2/8,512,0,stream>>>(t3,n2w,n2b,t2/*xn*/);
    // MLP2
    gemm_r5<1,0><<<MT*4,512,0,stream>>>(t2,wm1,m2b1,big/*m*/,nullptr,nullptr,M2,1024,512,4);
    gemm_r5<0,0><<<MT*2,512,0,stream>>>(big,wm2,m2b2,t0/*m2*/,nullptr,nullptr,M2,512,1024,2);
    // GCN2
    gemm_r5<0,0><<<MT*6,512,0,stream>>>(t0,wg2,gcn2_b,big/*G2*/,nullptr,nullptr,M2,1536,512,6);
    k_gcn2<1><<<NB/4,512,0,stream>>>(big,adj,nullptr,t3/*tsum*/,b0,out);
  }
}